// Round 8
// baseline (880.079 us; speedup 1.0000x reference)
//
#include <hip/hip_runtime.h>
#include <hip/hip_fp16.h>
#include <math.h>

// ---------------------------------------------------------------------------
// HybridBERT4RecGNN forward on MI355X (gfx950), round 8.
//
// Occupancy model pinned by R3-R7: co-residency needs (waves/SIMD)*VGPR <= 256
// per SIMD. 8-wave blocks can never get 2 blocks/CU without <=64 regs (spill).
// R8: 256-thread blocks (1 wave/SIMD per block), VGPR <= 85, LDS cut to
// ~50 KB (fp16 attn weights, K^T pitch 51, pitch-64 broadcast rows) ->
// 3 blocks/CU = 12 waves/CU, spill-free.
// GNN path unchanged (CSR build + gather).
// ---------------------------------------------------------------------------

#define SD   64   // model dim
#define SS   50   // seq len (MAXLEN)
#define DFF  256
#define NBLK 2
#define PXS  64   // pitch for broadcast-read row buffers (16B-aligned rows;
                  // lane-major writes + same-address reads: conflict-free)
#define PKV  65   // V pitch (column reads need odd pitch)
#define PKT  51   // K^T pitch (odd -> conflict-free strided access)
#define SCP  52   // scw pitch (in halves)
#define NWV  4    // waves per block
#define RPW  13   // max rows per wave

__device__ __forceinline__ float wred_sum(float v) {
#pragma unroll
  for (int o = 32; o > 0; o >>= 1) v += __shfl_xor(v, o, 64);
  return v;
}
__device__ __forceinline__ float2 wred_sum2(float a, float b) {
#pragma unroll
  for (int o = 32; o > 0; o >>= 1) {
    a += __shfl_xor(a, o, 64);
    b += __shfl_xor(b, o, 64);
  }
  return make_float2(a, b);
}
__device__ __forceinline__ float gelu_tanh(float x) {
  float u = 0.7978845608028654f * (x + 0.044715f * x * x * x);
  float a = fabsf(u);
  float e = __expf(-2.f * a);
  float th = copysignf((1.f - e) / (1.f + e), u);
  return 0.5f * x * (1.0f + th);
}

// 64-k projection for this wave's rows (input rows at pitch PXS), k-chunks of
// 8 so only wreg[8] is live (peak live regs ~ acc[13]+wreg[8]+temps < 85).
template <int LDW>
__device__ __forceinline__ void proj_rows(const float* in, const float* __restrict__ W,
                                          int lane, int wid, float acc[RPW]) {
#pragma unroll
  for (int ir = 0; ir < RPW; ++ir) acc[ir] = 0.f;
#pragma unroll 1
  for (int kh = 0; kh < 8; ++kh) {
    float wreg[8];
#pragma unroll
    for (int k = 0; k < 8; ++k) wreg[k] = W[(kh * 8 + k) * LDW + lane];
#pragma unroll
    for (int ir = 0; ir < RPW; ++ir) {
      int s = wid + NWV * ir;
      if (s < SS) {
        const float* row = in + s * PXS + kh * 8;
        float4 a = *(const float4*)(row);
        float4 b = *(const float4*)(row + 4);
        float t0 = a.x * wreg[0] + a.y * wreg[1];
        float t1 = a.z * wreg[2] + a.w * wreg[3];
        float t2 = b.x * wreg[4] + b.y * wreg[5];
        float t3 = b.z * wreg[6] + b.w * wreg[7];
        acc[ir] += (t0 + t1) + (t2 + t3);
      }
    }
  }
}

// ---------------------------------------------------------------------------
// GNN path A (preferred): CSR build + gather
// ---------------------------------------------------------------------------
__global__ void gnn_hist(const int* __restrict__ dst, int* __restrict__ cnt, int E) {
  int e = blockIdx.x * blockDim.x + threadIdx.x;
  if (e < E) atomicAdd(&cnt[dst[e]], 1);
}

__global__ void gnn_chunk_sums(const int* __restrict__ cnt, int* __restrict__ bsum) {
  __shared__ int ssum;
  if (threadIdx.x == 0) ssum = 0;
  __syncthreads();
  int base = blockIdx.x * 1024 + threadIdx.x * 4;
  int s = cnt[base] + cnt[base + 1] + cnt[base + 2] + cnt[base + 3];
#pragma unroll
  for (int o = 32; o > 0; o >>= 1) s += __shfl_xor(s, o, 64);
  if ((threadIdx.x & 63) == 0) atomicAdd(&ssum, s);
  __syncthreads();
  if (threadIdx.x == 0) bsum[blockIdx.x] = ssum;
}

__global__ void gnn_scan_bsum(int* __restrict__ bsum, int nch) {
  __shared__ int sb[128];
  int t = threadIdx.x;
  if (t < nch) sb[t] = bsum[t];
  __syncthreads();
  if (t == 0) {
    int a = 0;
    for (int i = 0; i < nch; ++i) { int v = sb[i]; sb[i] = a; a += v; }
  }
  __syncthreads();
  if (t < nch) bsum[t] = sb[t];
}

__global__ void gnn_chunk_scan(const int* __restrict__ cnt, const int* __restrict__ bofs,
                               int* __restrict__ rp, int* __restrict__ wp, int Nn) {
  __shared__ int wsum[4];
  int t = threadIdx.x, lane = t & 63, wv = t >> 6;
  int base = blockIdx.x * 1024 + t * 4;
  int c0 = cnt[base], c1 = cnt[base + 1], c2 = cnt[base + 2], c3 = cnt[base + 3];
  int s = c0 + c1 + c2 + c3;
  int x = s;  // inclusive wave scan
#pragma unroll
  for (int o = 1; o < 64; o <<= 1) {
    int y = __shfl_up(x, o, 64);
    if (lane >= o) x += y;
  }
  if (lane == 63) wsum[wv] = x;
  __syncthreads();
  int wo = 0;
#pragma unroll
  for (int i = 0; i < 4; ++i) if (i < wv) wo += wsum[i];
  int excl = bofs[blockIdx.x] + wo + (x - s);
  int p[4];
  p[0] = excl; p[1] = p[0] + c0; p[2] = p[1] + c1; p[3] = p[2] + c2;
#pragma unroll
  for (int j = 0; j < 4; ++j) {
    int idx = base + j;
    if (idx <= Nn) rp[idx] = p[j];
    if (idx < Nn) wp[idx] = p[j];
  }
}

__global__ void gnn_build(const int* __restrict__ src, const int* __restrict__ dst,
                          const float* __restrict__ ew, int* __restrict__ wp,
                          int* __restrict__ es, float* __restrict__ ewt, int E) {
  int e = blockIdx.x * blockDim.x + threadIdx.x;
  if (e >= E) return;
  int pos = atomicAdd(&wp[dst[e]], 1);
  es[pos] = src[e];
  ewt[pos] = ew[e];
}

__global__ void gnn_gather(const float* __restrict__ xin, const int* __restrict__ rp,
                           const int* __restrict__ es, const float* __restrict__ ewt,
                           float* __restrict__ xout, int Nn) {
  int n = blockIdx.x * 4 + (threadIdx.x >> 6);
  int lane = threadIdx.x & 63;
  if (n >= Nn) return;
  int beg = rp[n], end = rp[n + 1];
  float acc = 0.f;
  int e = beg;
  for (; e + 4 <= end; e += 4) {
    int s0 = es[e], s1 = es[e + 1], s2 = es[e + 2], s3 = es[e + 3];
    float w0 = ewt[e], w1 = ewt[e + 1], w2 = ewt[e + 2], w3 = ewt[e + 3];
    float x0 = xin[(size_t)s0 * SD + lane];
    float x1 = xin[(size_t)s1 * SD + lane];
    float x2 = xin[(size_t)s2 * SD + lane];
    float x3 = xin[(size_t)s3 * SD + lane];
    acc += x0 * w0 + x1 * w1 + x2 * w2 + x3 * w3;
  }
  for (; e < end; ++e) acc += xin[(size_t)es[e] * SD + lane] * ewt[e];
  xout[(size_t)n * SD + lane] = acc;
}

// ---------------------------------------------------------------------------
// GNN path B (fallback): atomic scatter
// ---------------------------------------------------------------------------
__global__ void gnn_scatter(const float* __restrict__ xin,
                            const int* __restrict__ src,
                            const int* __restrict__ dst,
                            const float* __restrict__ ew,
                            float* __restrict__ xout, int E) {
  int gid = blockIdx.x * blockDim.x + threadIdx.x;
  int e = gid >> 6;
  int d = gid & 63;
  if (e >= E) return;
  atomicAdd(&xout[(size_t)dst[e] * SD + d], xin[(size_t)src[e] * SD + d] * ew[e]);
}

// ---------------------------------------------------------------------------
// Per-sequence fused kernel. 256 threads = 4 waves; wave w owns rows
// s = w + 4*ir (ir < 13); lane = feature/column index.
// LDS: xs 12800 + bufA 13600 + bufB 13056 + scw 10400 + sidx 200 = 50,056 B
// -> 3 blocks/CU (150 KB <= 160 KB). VGPR must be <= 85 for 3 waves/SIMD
// (empirical pool: waves/SIMD * VGPR <= 256).
// ---------------------------------------------------------------------------
__global__ __launch_bounds__(256, 3)
void seq_transformer(const int* __restrict__ seq, const int* __restrict__ lengths,
                     const float* __restrict__ bert, const float* __restrict__ gnn,
                     const float* __restrict__ g1x, const float* __restrict__ g2x,
                     const float* __restrict__ pw, const float* __restrict__ pbias,
                     const float* __restrict__ pos,
                     const float* __restrict__ wq, const float* __restrict__ wk,
                     const float* __restrict__ wv, const float* __restrict__ wo,
                     const float* __restrict__ w1, const float* __restrict__ b1,
                     const float* __restrict__ w2, const float* __restrict__ b2,
                     const float* __restrict__ ln1g, const float* __restrict__ ln1b,
                     const float* __restrict__ ln2g, const float* __restrict__ ln2b,
                     const float* __restrict__ lnfg, const float* __restrict__ lnfb,
                     float* __restrict__ out) {
  __shared__ float  xs[SS * PXS];      // hidden state, p64
  __shared__ float  bufA[3400];        // Q (p64) / V (p65) / ffn-h (p64) / gnn tmp
  __shared__ float  bufB[3264];        // K^T (64 x 50, p51)  /  ctx (p64)
  __shared__ __half scw[2 * SS * SCP]; // attn scores/weights, fp16 [2][50][52]
  __shared__ int    sidx[SS];

  const int t = threadIdx.x;
  const int lane = t & 63;
  const int wid = t >> 6;
  const int b = blockIdx.x;

  if (t < SS) sidx[t] = seq[b * SS + t];
  __syncthreads();

  const int len = lengths[b];
  const float alpha = (len <= 10) ? 0.3f : ((len >= 50) ? 0.7f : 0.5f);
  const float one_m_alpha = 1.0f - alpha;

  float acc[RPW];

  // ---- phase 0a: averaged GNN rows for this sequence's tokens -> bufA (p64)
#pragma unroll
  for (int ir = 0; ir < RPW; ++ir) {
    int s = wid + NWV * ir;
    if (s < SS) {
      size_t base = (size_t)sidx[s] * SD + lane;
      bufA[s * PXS + lane] = (gnn[base] + g1x[base] + g2x[base]) * (1.0f / 3.0f);
    }
  }
  __syncthreads();

  // ---- phase 0b: gnn projection + discrete-alpha blend + pos emb -> xs
  proj_rows<SD>(bufA, pw, lane, wid, acc);
  {
    float pbv = pbias[lane];
#pragma unroll
    for (int ir = 0; ir < RPW; ++ir) {
      int s = wid + NWV * ir;
      if (s < SS) {
        float g = acc[ir] + pbv;
        size_t base = (size_t)sidx[s] * SD + lane;
        xs[s * PXS + lane] = alpha * bert[base] + one_m_alpha * g + pos[s * SD + lane];
      }
    }
  }
  __syncthreads();

  const float inv_sqrt_dh = 0.17677669529663687f;  // 1/sqrt(32)

#pragma unroll 1
  for (int blk = 0; blk < NBLK; ++blk) {
    const float* Wq = wq + blk * SD * SD;
    const float* Wk = wk + blk * SD * SD;
    const float* Wv = wv + blk * SD * SD;
    const float* Wo = wo + blk * SD * SD;
    const float* W1 = w1 + blk * SD * DFF;
    const float* B1 = b1 + blk * DFF;
    const float* W2 = w2 + blk * DFF * SD;
    const float* B2 = b2 + blk * SD;

    // ---- Q -> bufA (p64)
    proj_rows<SD>(xs, Wq, lane, wid, acc);
#pragma unroll
    for (int ir = 0; ir < RPW; ++ir) {
      int s = wid + NWV * ir;
      if (s < SS) bufA[s * PXS + lane] = acc[ir];
    }
    // ---- K^T -> bufB (p51; odd pitch -> conflict-free strided writes/reads)
    proj_rows<SD>(xs, Wk, lane, wid, acc);
#pragma unroll
    for (int ir = 0; ir < RPW; ++ir) {
      int s = wid + NWV * ir;
      if (s < SS) bufB[lane * PKT + s] = acc[ir];
    }
    __syncthreads();

    // ---- scores: wave rows = sq, lane = sk. K column in registers,
    //      k-chunks of 8; fp16 store to scw.
    {
      const int sk = lane;
      const bool skv = (sk < SS);
      const int skc = skv ? sk : 0;                 // clamp to stay in bufB
      const bool kmask = skv && (sidx[skc] != 0);
#pragma unroll 1
      for (int h = 0; h < 2; ++h) {
        float sc[RPW];
#pragma unroll
        for (int ir = 0; ir < RPW; ++ir) sc[ir] = 0.f;
#pragma unroll 1
        for (int dc = 0; dc < 4; ++dc) {
          float kr[8];
#pragma unroll
          for (int dh = 0; dh < 8; ++dh)
            kr[dh] = bufB[(h * 32 + dc * 8 + dh) * PKT + skc];
#pragma unroll
          for (int ir = 0; ir < RPW; ++ir) {
            int sq = wid + NWV * ir;
            if (sq < SS) {
              const float* qrow = &bufA[sq * PXS + h * 32 + dc * 8];
              float4 qa = *(const float4*)(qrow);
              float4 qb = *(const float4*)(qrow + 4);
              float t0 = qa.x * kr[0] + qa.y * kr[1];
              float t1 = qa.z * kr[2] + qa.w * kr[3];
              float t2 = qb.x * kr[4] + qb.y * kr[5];
              float t3 = qb.z * kr[6] + qb.w * kr[7];
              sc[ir] += (t0 + t1) + (t2 + t3);
            }
          }
        }
#pragma unroll
        for (int ir = 0; ir < RPW; ++ir) {
          int sq = wid + NWV * ir;
          if (sq < SS && skv)
            scw[(h * SS + sq) * SCP + sk] =
                __float2half(kmask ? sc[ir] * inv_sqrt_dh : -60000.f);
        }
      }
    }
    __syncthreads();

    // ---- softmax: wave per (h,sq) row, lane = sk; rows in independent pairs
    {
      int r = wid;
#pragma unroll 1
      for (; r + NWV < 2 * SS; r += 2 * NWV) {
        float v0 = (lane < SS) ? __half2float(scw[r * SCP + lane]) : -1e30f;
        float v1 = (lane < SS) ? __half2float(scw[(r + NWV) * SCP + lane]) : -1e30f;
        float m0 = v0, m1 = v1;
#pragma unroll
        for (int o = 32; o > 0; o >>= 1) {
          m0 = fmaxf(m0, __shfl_xor(m0, o, 64));
          m1 = fmaxf(m1, __shfl_xor(m1, o, 64));
        }
        float e0 = (lane < SS) ? __expf(v0 - m0) : 0.f;
        float e1 = (lane < SS) ? __expf(v1 - m1) : 0.f;
        float2 sm = wred_sum2(e0, e1);
        if (lane < SCP) {
          scw[r * SCP + lane] = __float2half(e0 / sm.x);  // cols 50,51 -> 0
          scw[(r + NWV) * SCP + lane] = __float2half(e1 / sm.y);
        }
      }
      if (r < 2 * SS) {
        float v = (lane < SS) ? __half2float(scw[r * SCP + lane]) : -1e30f;
        float mx = v;
#pragma unroll
        for (int o = 32; o > 0; o >>= 1) mx = fmaxf(mx, __shfl_xor(mx, o, 64));
        float e = (lane < SS) ? __expf(v - mx) : 0.f;
        float sm = wred_sum(e);
        if (lane < SCP) scw[r * SCP + lane] = __float2half(e / sm);
      }
    }
    __syncthreads();

    // ---- V -> bufA (p65; overwrites consumed Q)
    proj_rows<SD>(xs, Wv, lane, wid, acc);
#pragma unroll
    for (int ir = 0; ir < RPW; ++ir) {
      int s = wid + NWV * ir;
      if (s < SS) bufA[s * PKV + lane] = acc[ir];
    }
    __syncthreads();

    // ---- ctx = attn @ V -> bufB (p64; overwrites consumed K^T).
    //      attn cols 50,51 are exact zeros; stale v-rows 50,51 are finite.
#pragma unroll
    for (int ir = 0; ir < RPW; ++ir) {
      int sq = wid + NWV * ir;
      if (sq < SS) {
        const int hb = (lane >> 5) * SS * SCP;
        float ax = 0.f, ay = 0.f, az = 0.f, aw = 0.f;
#pragma unroll
        for (int j = 0; j < 13; ++j) {
          const __half2* ph = (const __half2*)&scw[hb + sq * SCP + 4 * j];
          float2 f01 = __half22float2(ph[0]);
          float2 f23 = __half22float2(ph[1]);
          ax += f01.x * bufA[(4 * j + 0) * PKV + lane];
          ay += f01.y * bufA[(4 * j + 1) * PKV + lane];
          az += f23.x * bufA[(4 * j + 2) * PKV + lane];
          aw += f23.y * bufA[(4 * j + 3) * PKV + lane];
        }
        bufB[sq * PXS + lane] = (ax + ay) + (az + aw);
      }
    }
    __syncthreads();

    // ---- O-projection + residual + LN1 -> xs
    proj_rows<SD>(bufB, Wo, lane, wid, acc);
    {
      float gv = ln1g[blk * SD + lane], bv = ln1b[blk * SD + lane];
#pragma unroll
      for (int ir = 0; ir < RPW; ++ir) {
        int s = wid + NWV * ir;
        if (s < SS) {
          float val = xs[s * PXS + lane] + acc[ir];
          float2 ss = wred_sum2(val, val * val);
          float m = ss.x * (1.f / 64);
          float var = fmaxf(ss.y * (1.f / 64) - m * m, 0.f);
          float rs = rsqrtf(var + 1e-5f);
          xs[s * PXS + lane] = (val - m) * rs * gv + bv;
        }
      }
    }
    __syncthreads();

    // ---- FFN: 4 chunks of 64 hidden dims; h staged in bufA (p64),
    //      out accumulated in registers across chunks.
    float acc2[RPW];
#pragma unroll
    for (int ir = 0; ir < RPW; ++ir) acc2[ir] = 0.f;
#pragma unroll 1
    for (int c = 0; c < 4; ++c) {
      proj_rows<DFF>(xs, W1 + c * 64, lane, wid, acc);
      float b1v = B1[c * 64 + lane];
#pragma unroll
      for (int ir = 0; ir < RPW; ++ir) {
        int s = wid + NWV * ir;
        if (s < SS) bufA[s * PXS + lane] = gelu_tanh(acc[ir] + b1v);
      }
      __syncthreads();
      proj_rows<SD>(bufA, W2 + c * 64 * SD, lane, wid, acc);
#pragma unroll
      for (int ir = 0; ir < RPW; ++ir) acc2[ir] += acc[ir];
      __syncthreads();
    }

    // ---- residual + LN2 -> xs
    {
      float gv = ln2g[blk * SD + lane], bv = ln2b[blk * SD + lane];
      float b2v = B2[lane];
#pragma unroll
      for (int ir = 0; ir < RPW; ++ir) {
        int s = wid + NWV * ir;
        if (s < SS) {
          float val = xs[s * PXS + lane] + acc2[ir] + b2v;
          float2 ss = wred_sum2(val, val * val);
          float m = ss.x * (1.f / 64);
          float var = fmaxf(ss.y * (1.f / 64) - m * m, 0.f);
          float rs = rsqrtf(var + 1e-5f);
          xs[s * PXS + lane] = (val - m) * rs * gv + bv;
        }
      }
    }
    __syncthreads();
  }

  // ---- final LN + gather row (lengths-1)
  if (wid == 0) {
    int sl = len - 1;
    float val = xs[sl * PXS + lane];
    float2 ss = wred_sum2(val, val * val);
    float m = ss.x * (1.f / 64);
    float var = fmaxf(ss.y * (1.f / 64) - m * m, 0.f);
    float rs = rsqrtf(var + 1e-5f);
    out[b * SD + lane] = (val - m) * rs * lnfg[lane] + lnfb[lane];
  }
}

// ---------------------------------------------------------------------------
extern "C" void kernel_launch(void* const* d_in, const int* in_sizes, int n_in,
                              void* d_out, int out_size, void* d_ws, size_t ws_size,
                              hipStream_t stream) {
  const int*   seq   = (const int*)d_in[0];
  const int*   lens  = (const int*)d_in[1];
  const int*   ei    = (const int*)d_in[2];
  const float* ew    = (const float*)d_in[3];
  const float* bert  = (const float*)d_in[4];
  const float* gnn   = (const float*)d_in[5];
  const float* pw    = (const float*)d_in[6];
  const float* pb    = (const float*)d_in[7];
  const float* pos   = (const float*)d_in[8];
  const float* wq    = (const float*)d_in[9];
  const float* wk    = (const float*)d_in[10];
  const float* wv    = (const float*)d_in[11];
  const float* wo    = (const float*)d_in[12];
  const float* w1    = (const float*)d_in[13];
  const float* b1    = (const float*)d_in[14];
  const float* w2    = (const float*)d_in[15];
  const float* b2    = (const float*)d_in[16];
  const float* ln1g  = (const float*)d_in[17];
  const float* ln1b  = (const float*)d_in[18];
  const float* ln2g  = (const float*)d_in[19];
  const float* ln2b  = (const float*)d_in[20];
  const float* lnfg  = (const float*)d_in[21];
  const float* lnfb  = (const float*)d_in[22];
  float* out = (float*)d_out;

  const int E = in_sizes[2] / 2;          // 1,000,000
  const int B = in_sizes[0] / SS;         // 1024
  const int N = in_sizes[4] / SD;         // 100,001

  const int*   esrc = ei;
  const int*   edst = ei + E;

  // ---- workspace layout
  float* g1x = (float*)d_ws;                       // N x 64
  float* g2x = g1x + (size_t)N * SD;               // N x 64
  const int NCH = (N + 1023) >> 10;                // scan chunks of 1024
  const int PADN = NCH << 10;                      // padded count array size
  int*   cnt  = (int*)(g2x + (size_t)N * SD);      // PADN
  int*   bsum = cnt + PADN;                        // NCH (<=128)
  int*   rp   = bsum + 128;                        // N+1
  int*   wp   = rp + (N + 1);                      // N
  int*   es   = wp + N;                            // E
  float* ewt  = (float*)(es + E);                  // E
  size_t need = (size_t)((char*)(ewt + E) - (char*)d_ws);

  if (ws_size >= need && NCH <= 128) {
    // ---- CSR build + gather (no atomics in the heavy passes)
    hipMemsetAsync(cnt, 0, (size_t)PADN * sizeof(int), stream);
    const int gb = (E + 255) / 256;
    gnn_hist<<<gb, 256, 0, stream>>>(edst, cnt, E);
    gnn_chunk_sums<<<NCH, 256, 0, stream>>>(cnt, bsum);
    gnn_scan_bsum<<<1, 128, 0, stream>>>(bsum, NCH);
    gnn_chunk_scan<<<NCH, 256, 0, stream>>>(cnt, bsum, rp, wp, N);
    gnn_build<<<gb, 256, 0, stream>>>(esrc, edst, ew, wp, es, ewt, E);
    const int nb = (N + 3) / 4;
    gnn_gather<<<nb, 256, 0, stream>>>(gnn, rp, es, ewt, g1x, N);
    gnn_gather<<<nb, 256, 0, stream>>>(g1x, rp, es, ewt, g2x, N);
  } else {
    // ---- fallback: atomic scatter
    hipMemsetAsync(g1x, 0, (size_t)2 * N * SD * sizeof(float), stream);
    const long total = (long)E * 64;
    const int sblocks = (int)((total + 255) / 256);
    gnn_scatter<<<sblocks, 256, 0, stream>>>(gnn, esrc, edst, ew, g1x, E);
    gnn_scatter<<<sblocks, 256, 0, stream>>>(g1x, esrc, edst, ew, g2x, E);
  }

  seq_transformer<<<B, 256, 0, stream>>>(
      seq, lens, bert, gnn, g1x, g2x, pw, pb, pos,
      wq, wk, wv, wo, w1, b1, w2, b2,
      ln1g, ln1b, ln2g, ln2b, lnfg, lnfb, out);
}

// Round 9
// 505.306 us; speedup vs baseline: 1.7417x; 1.7417x over previous
//
#include <hip/hip_runtime.h>
#include <math.h>

// ---------------------------------------------------------------------------
// HybridBERT4RecGNN forward on MI355X (gfx950), round 9.
//
// R8 post-mortem: fp32-VALU formulation plateaued (~600 us, VALUBusy 59%,
// mostly non-FMA overhead). R9: bf16 MFMA (v_mfma_f32_16x16x32_bf16) for all
// dense GEMMs + QK^T + PV. Weights pre-converted once per launch into
// B-fragment-major bf16 tiles in d_ws. x/Q/K/V/P in LDS bf16 pitch-72
// (16B-aligned A/B-frag b128 reads, <=2-way banks). LDS 46.3 KB -> up to
// 3 blocks/CU. LN in C-layout regs via intra-quad butterflies.
// GNN path unchanged (CSR build + gather).
//
// Fragment layouts (gfx950, verified per guide):
//   A (16x32): lane holds A[m][k], m=lane&15, k=(lane>>4)*8+j
//   B (32x16): lane holds B[k][n], n=lane&15, k=(lane>>4)*8+j
//   D (16x16): lane holds D[m][n], n=lane&15, m=(lane>>4)*4+reg
// ---------------------------------------------------------------------------

typedef __attribute__((ext_vector_type(8))) short bf16x8;
typedef __attribute__((ext_vector_type(4))) float f32x4;

#define SD   64
#define SS   50
#define NBLK 2
#define PH   72    // LDS pitch in halves (144 B, 16B-aligned, bank-friendly)

__device__ __forceinline__ short f2b(float f) {  // fp32 -> bf16 RNE
  union { float f; unsigned u; } v; v.f = f;
  unsigned r = v.u + 0x7FFFu + ((v.u >> 16) & 1u);
  return (short)(r >> 16);
}
__device__ __forceinline__ float b2f(short s) {
  union { unsigned u; float f; } v;
  v.u = ((unsigned)(unsigned short)s) << 16;
  return v.f;
}
__device__ __forceinline__ float wred_sum(float v) {
#pragma unroll
  for (int o = 32; o > 0; o >>= 1) v += __shfl_xor(v, o, 64);
  return v;
}
__device__ __forceinline__ float wred_max(float v) {
#pragma unroll
  for (int o = 32; o > 0; o >>= 1) v = fmaxf(v, __shfl_xor(v, o, 64));
  return v;
}
__device__ __forceinline__ float2 wred_sum2(float a, float b) {
#pragma unroll
  for (int o = 32; o > 0; o >>= 1) {
    a += __shfl_xor(a, o, 64);
    b += __shfl_xor(b, o, 64);
  }
  return make_float2(a, b);
}
__device__ __forceinline__ float gelu_tanh(float x) {
  float u = 0.7978845608028654f * (x + 0.044715f * x * x * x);
  float a = fabsf(u);
  float e = __expf(-2.f * a);
  float th = copysignf((1.f - e) / (1.f + e), u);
  return 0.5f * x * (1.0f + th);
}

// B-frag load: tiles stored tile-major, 64 lanes x 8 halves contiguous.
__device__ __forceinline__ bf16x8 ldB(const short* __restrict__ Wb, int tile, int lane) {
  return *(const bf16x8*)(Wb + ((size_t)tile * 64 + lane) * 8);
}

// [64xK=64] @ [64x64]: 4 nt tiles, 2 kt steps. A from LDS bf16 pitch PH.
__device__ __forceinline__ void mm64(const short* A, const short* __restrict__ Wb,
                                     int arow, int quad, int lane, f32x4 o4[4]) {
  bf16x8 a0 = *(const bf16x8*)(A + arow * PH + quad * 8);
  bf16x8 a1 = *(const bf16x8*)(A + arow * PH + 32 + quad * 8);
#pragma unroll
  for (int nt = 0; nt < 4; ++nt) {
    f32x4 acc = {0.f, 0.f, 0.f, 0.f};
    acc = __builtin_amdgcn_mfma_f32_16x16x32_bf16(a0, ldB(Wb, 0 * 4 + nt, lane), acc, 0, 0, 0);
    acc = __builtin_amdgcn_mfma_f32_16x16x32_bf16(a1, ldB(Wb, 1 * 4 + nt, lane), acc, 0, 0, 0);
    o4[nt] = acc;
  }
}

// LN over cols (64) of D-layout values + residual(from xh bf16) + optional bias.
__device__ __forceinline__ void ln_epilogue(f32x4 o4[4], short* xh,
                                            const float* __restrict__ g,
                                            const float* __restrict__ bta,
                                            const float* __restrict__ extrab,
                                            int mt, int quad, int c0) {
  float vals[4][4];
  float s1[4] = {0.f, 0.f, 0.f, 0.f}, s2[4] = {0.f, 0.f, 0.f, 0.f};
#pragma unroll
  for (int nt = 0; nt < 4; ++nt) {
    int c = nt * 16 + c0;
    float eb = extrab ? extrab[c] : 0.f;
#pragma unroll
    for (int r = 0; r < 4; ++r) {
      int row = mt * 16 + quad * 4 + r;
      float v = o4[nt][r] + b2f(xh[row * PH + c]) + eb;
      vals[nt][r] = v;
      s1[r] += v;
      s2[r] += v * v;
    }
  }
#pragma unroll
  for (int o = 1; o < 16; o <<= 1) {
#pragma unroll
    for (int r = 0; r < 4; ++r) {
      s1[r] += __shfl_xor(s1[r], o, 64);
      s2[r] += __shfl_xor(s2[r], o, 64);
    }
  }
  float mv[4], rv[4];
#pragma unroll
  for (int r = 0; r < 4; ++r) {
    float m = s1[r] * (1.f / 64);
    float var = fmaxf(s2[r] * (1.f / 64) - m * m, 0.f);
    mv[r] = m;
    rv[r] = rsqrtf(var + 1e-5f);
  }
#pragma unroll
  for (int nt = 0; nt < 4; ++nt) {
    int c = nt * 16 + c0;
    float gv = g[c], bv = bta[c];
#pragma unroll
    for (int r = 0; r < 4; ++r) {
      int row = mt * 16 + quad * 4 + r;
      xh[row * PH + c] = f2b((vals[nt][r] - mv[r]) * rv[r] * gv + bv);
    }
  }
}

// ---------------------------------------------------------------------------
// Weight prep: W row-major [K][N] fp32 (nmat mats contiguous) -> bf16
// B-frag-major tiles: out[(((m*KT+kt)*NT+nt)*64+lane)*8 + j]
//   = bf16( W_m[kt*32 + (lane>>4)*8 + j][nt*16 + (lane&15)] )
// ---------------------------------------------------------------------------
__global__ void prep_b(const float* __restrict__ W, int K, int N, int nmat,
                       short* __restrict__ out) {
  int KT = K / 32, NT = N / 16;
  int tid = blockIdx.x * blockDim.x + threadIdx.x;
  int total = nmat * KT * NT * 64;
  if (tid >= total) return;
  int lane = tid & 63;
  int tt = tid >> 6;
  int nt = tt % NT; tt /= NT;
  int kt = tt % KT; tt /= KT;
  int m = tt;
  const float* Wm = W + (size_t)m * K * N;
  int kbase = kt * 32 + ((lane >> 4) * 8);
  int n = nt * 16 + (lane & 15);
  short v[8];
#pragma unroll
  for (int j = 0; j < 8; ++j) v[j] = f2b(Wm[(size_t)(kbase + j) * N + n]);
  *(bf16x8*)(out + (size_t)tid * 8) = *(bf16x8*)v;
}

// ---------------------------------------------------------------------------
// GNN path A: CSR build + gather (unchanged from R8)
// ---------------------------------------------------------------------------
__global__ void gnn_hist(const int* __restrict__ dst, int* __restrict__ cnt, int E) {
  int e = blockIdx.x * blockDim.x + threadIdx.x;
  if (e < E) atomicAdd(&cnt[dst[e]], 1);
}

__global__ void gnn_chunk_sums(const int* __restrict__ cnt, int* __restrict__ bsum) {
  __shared__ int ssum;
  if (threadIdx.x == 0) ssum = 0;
  __syncthreads();
  int base = blockIdx.x * 1024 + threadIdx.x * 4;
  int s = cnt[base] + cnt[base + 1] + cnt[base + 2] + cnt[base + 3];
#pragma unroll
  for (int o = 32; o > 0; o >>= 1) s += __shfl_xor(s, o, 64);
  if ((threadIdx.x & 63) == 0) atomicAdd(&ssum, s);
  __syncthreads();
  if (threadIdx.x == 0) bsum[blockIdx.x] = ssum;
}

__global__ void gnn_scan_bsum(int* __restrict__ bsum, int nch) {
  __shared__ int sb[128];
  int t = threadIdx.x;
  if (t < nch) sb[t] = bsum[t];
  __syncthreads();
  if (t == 0) {
    int a = 0;
    for (int i = 0; i < nch; ++i) { int v = sb[i]; sb[i] = a; a += v; }
  }
  __syncthreads();
  if (t < nch) bsum[t] = sb[t];
}

__global__ void gnn_chunk_scan(const int* __restrict__ cnt, const int* __restrict__ bofs,
                               int* __restrict__ rp, int* __restrict__ wp, int Nn) {
  __shared__ int wsum[4];
  int t = threadIdx.x, lane = t & 63, wv = t >> 6;
  int base = blockIdx.x * 1024 + t * 4;
  int c0 = cnt[base], c1 = cnt[base + 1], c2 = cnt[base + 2], c3 = cnt[base + 3];
  int s = c0 + c1 + c2 + c3;
  int x = s;
#pragma unroll
  for (int o = 1; o < 64; o <<= 1) {
    int y = __shfl_up(x, o, 64);
    if (lane >= o) x += y;
  }
  if (lane == 63) wsum[wv] = x;
  __syncthreads();
  int wo = 0;
#pragma unroll
  for (int i = 0; i < 4; ++i) if (i < wv) wo += wsum[i];
  int excl = bofs[blockIdx.x] + wo + (x - s);
  int p[4];
  p[0] = excl; p[1] = p[0] + c0; p[2] = p[1] + c1; p[3] = p[2] + c2;
#pragma unroll
  for (int j = 0; j < 4; ++j) {
    int idx = base + j;
    if (idx <= Nn) rp[idx] = p[j];
    if (idx < Nn) wp[idx] = p[j];
  }
}

__global__ void gnn_build(const int* __restrict__ src, const int* __restrict__ dst,
                          const float* __restrict__ ew, int* __restrict__ wp,
                          int* __restrict__ es, float* __restrict__ ewt, int E) {
  int e = blockIdx.x * blockDim.x + threadIdx.x;
  if (e >= E) return;
  int pos = atomicAdd(&wp[dst[e]], 1);
  es[pos] = src[e];
  ewt[pos] = ew[e];
}

__global__ void gnn_gather(const float* __restrict__ xin, const int* __restrict__ rp,
                           const int* __restrict__ es, const float* __restrict__ ewt,
                           float* __restrict__ xout, int Nn) {
  int n = blockIdx.x * 4 + (threadIdx.x >> 6);
  int lane = threadIdx.x & 63;
  if (n >= Nn) return;
  int beg = rp[n], end = rp[n + 1];
  float acc = 0.f;
  int e = beg;
  for (; e + 4 <= end; e += 4) {
    int s0 = es[e], s1 = es[e + 1], s2 = es[e + 2], s3 = es[e + 3];
    float w0 = ewt[e], w1 = ewt[e + 1], w2 = ewt[e + 2], w3 = ewt[e + 3];
    acc += xin[(size_t)s0 * SD + lane] * w0 + xin[(size_t)s1 * SD + lane] * w1 +
           xin[(size_t)s2 * SD + lane] * w2 + xin[(size_t)s3 * SD + lane] * w3;
  }
  for (; e < end; ++e) acc += xin[(size_t)es[e] * SD + lane] * ewt[e];
  xout[(size_t)n * SD + lane] = acc;
}

__global__ void gnn_scatter(const float* __restrict__ xin,
                            const int* __restrict__ src,
                            const int* __restrict__ dst,
                            const float* __restrict__ ew,
                            float* __restrict__ xout, int E) {
  int gid = blockIdx.x * blockDim.x + threadIdx.x;
  int e = gid >> 6;
  int d = gid & 63;
  if (e >= E) return;
  atomicAdd(&xout[(size_t)dst[e] * SD + d], xin[(size_t)src[e] * SD + d] * ew[e]);
}

// ---------------------------------------------------------------------------
// MFMA transformer: 256 threads = 4 waves; wave = mt (row-tile 0..3).
// LDS: 5 x 64x72 bf16 + sidx = 46,336 B. Garbage rows 50-63 stay finite
// (row isolation of MFMA; P cols >=50 forced to 0 by softmax).
// ---------------------------------------------------------------------------
__global__ __launch_bounds__(256, 6)
void seq_transformer(const int* __restrict__ seq, const int* __restrict__ lengths,
                     const float* __restrict__ bert, const float* __restrict__ gnn,
                     const float* __restrict__ g1x, const float* __restrict__ g2x,
                     const float* __restrict__ pbias, const float* __restrict__ pos,
                     const short* __restrict__ pwB, const short* __restrict__ wqB,
                     const short* __restrict__ wkB, const short* __restrict__ wvB,
                     const short* __restrict__ woB, const short* __restrict__ w1B,
                     const short* __restrict__ w2B,
                     const float* __restrict__ b1, const float* __restrict__ b2,
                     const float* __restrict__ ln1g, const float* __restrict__ ln1b,
                     const float* __restrict__ ln2g, const float* __restrict__ ln2b,
                     const float* __restrict__ lnfg, const float* __restrict__ lnfb,
                     float* __restrict__ out) {
  __shared__ short xh[64 * PH];   // x (bf16)
  __shared__ short qh[64 * PH];   // gnn-avg / Q / ctx / ffn-h
  __shared__ short kh[64 * PH];   // K / scores-h1 (repurposed)
  __shared__ short vt[64 * PH];   // V^T [dim][seq]
  __shared__ short s0[64 * PH];   // scores-h0
  __shared__ int   sidx[64];

  const int t = threadIdx.x;
  const int lane = t & 63;
  const int mt = t >> 6;
  const int quad = lane >> 4;
  const int c0 = lane & 15;
  const int b = blockIdx.x;
  const int arow = mt * 16 + c0;

  if (t < 64) sidx[t] = (t < SS) ? seq[b * SS + t] : 0;
  __syncthreads();

  const int len = lengths[b];
  const float alpha = (len <= 10) ? 0.3f : ((len >= 50) ? 0.7f : 0.5f);
  const float isq = 0.17677669529663687f;  // 1/sqrt(32)

  // ---- phase 0a: averaged GNN rows -> qh (bf16), rows >= 50 zeroed
#pragma unroll
  for (int ir = 0; ir < 16; ++ir) {
    int s = mt + 4 * ir;
    short v = 0;
    if (s < SS) {
      size_t base = (size_t)sidx[s] * SD + lane;
      v = f2b((gnn[base] + g1x[base] + g2x[base]) * (1.f / 3.f));
    }
    qh[s * PH + lane] = v;
  }
  __syncthreads();

  // ---- phase 0b: gnn projection (MFMA) + blend + pos -> xh
  {
    f32x4 o4[4];
    mm64(qh, pwB, arow, quad, lane, o4);
#pragma unroll
    for (int nt = 0; nt < 4; ++nt) {
      int c = nt * 16 + c0;
      float pbv = pbias[c];
#pragma unroll
      for (int r = 0; r < 4; ++r) {
        int row = mt * 16 + quad * 4 + r;
        short ov = 0;
        if (row < SS) {
          float g = o4[nt][r] + pbv;
          float xv = alpha * bert[(size_t)sidx[row] * SD + c] +
                     (1.f - alpha) * g + pos[row * SD + c];
          ov = f2b(xv);
        }
        xh[row * PH + c] = ov;
      }
    }
  }
  __syncthreads();

#pragma unroll 1
  for (int blk = 0; blk < NBLK; ++blk) {
    const short* Wq = wqB + blk * 4096;
    const short* Wk = wkB + blk * 4096;
    const short* Wv = wvB + blk * 4096;
    const short* Wo = woB + blk * 4096;
    const short* W1 = w1B + blk * 16384;
    const short* W2 = w2B + blk * 16384;

    // ---- Q -> qh, K -> kh (row-major), V -> vt (transposed)
    {
      f32x4 o4[4];
      mm64(xh, Wq, arow, quad, lane, o4);
#pragma unroll
      for (int nt = 0; nt < 4; ++nt) {
        int c = nt * 16 + c0;
#pragma unroll
        for (int r = 0; r < 4; ++r) qh[(mt * 16 + quad * 4 + r) * PH + c] = f2b(o4[nt][r]);
      }
      mm64(xh, Wk, arow, quad, lane, o4);
#pragma unroll
      for (int nt = 0; nt < 4; ++nt) {
        int c = nt * 16 + c0;
#pragma unroll
        for (int r = 0; r < 4; ++r) kh[(mt * 16 + quad * 4 + r) * PH + c] = f2b(o4[nt][r]);
      }
      mm64(xh, Wv, arow, quad, lane, o4);
#pragma unroll
      for (int nt = 0; nt < 4; ++nt) {
        int dim = nt * 16 + c0;
        unsigned p0 = ((unsigned)(unsigned short)f2b(o4[nt][0])) |
                      (((unsigned)(unsigned short)f2b(o4[nt][1])) << 16);
        unsigned p1 = ((unsigned)(unsigned short)f2b(o4[nt][2])) |
                      (((unsigned)(unsigned short)f2b(o4[nt][3])) << 16);
        *(uint2*)(vt + (size_t)dim * PH + mt * 16 + quad * 4) = make_uint2(p0, p1);
      }
    }
    __syncthreads();

    // ---- scores: S_h = Q_h K_h^T (K=32, 1 MFMA/tile).
    //      h0 written to s0 immediately (fresh buffer); h1 computed, then
    //      barrier, then written into kh (repurposed).
    {
      bf16x8 aq0 = *(const bf16x8*)(qh + arow * PH + quad * 8);
      bf16x8 aq1 = *(const bf16x8*)(qh + arow * PH + 32 + quad * 8);
      f32x4 sa1[4];
#pragma unroll
      for (int nt = 0; nt < 4; ++nt) {
        int key = nt * 16 + c0;
        bf16x8 bk0 = *(const bf16x8*)(kh + key * PH + quad * 8);
        f32x4 acc = {0.f, 0.f, 0.f, 0.f};
        acc = __builtin_amdgcn_mfma_f32_16x16x32_bf16(aq0, bk0, acc, 0, 0, 0);
        bool km = (key < SS) && (sidx[key] != 0);
#pragma unroll
        for (int r = 0; r < 4; ++r) {
          int q = mt * 16 + quad * 4 + r;
          s0[q * PH + key] = f2b(km ? acc[r] * isq : -1e9f);
        }
        bf16x8 bk1 = *(const bf16x8*)(kh + key * PH + 32 + quad * 8);
        f32x4 acc1 = {0.f, 0.f, 0.f, 0.f};
        sa1[nt] = __builtin_amdgcn_mfma_f32_16x16x32_bf16(aq1, bk1, acc1, 0, 0, 0);
      }
      __syncthreads();  // all waves done reading kh
#pragma unroll
      for (int nt = 0; nt < 4; ++nt) {
        int key = nt * 16 + c0;
        bool km = (key < SS) && (sidx[key] != 0);
#pragma unroll
        for (int r = 0; r < 4; ++r) {
          int q = mt * 16 + quad * 4 + r;
          kh[q * PH + key] = f2b(km ? sa1[nt][r] * isq : -1e9f);
        }
      }
    }
    __syncthreads();

    // ---- softmax: 100 rows over 4 waves; writes all 64 key-lanes so
    //      P cols 50-63 become exact zeros.
#pragma unroll 1
    for (int i = mt; i < 2 * SS; i += 4) {
      short* buf = (i < SS) ? s0 : kh;
      int r = (i < SS) ? i : i - SS;
      float v = (lane < SS) ? b2f(buf[r * PH + lane]) : -1e30f;
      float mx = wred_max(v);
      float e = (lane < SS) ? __expf(v - mx) : 0.f;
      float sm = wred_sum(e);
      buf[r * PH + lane] = f2b(e / sm);
    }
    __syncthreads();

    // ---- ctx = P V -> qh (A-layout, row-major)
#pragma unroll
    for (int h = 0; h < 2; ++h) {
      const short* P = h ? kh : s0;
      bf16x8 a0 = *(const bf16x8*)(P + arow * PH + quad * 8);
      bf16x8 a1 = *(const bf16x8*)(P + arow * PH + 32 + quad * 8);
#pragma unroll
      for (int nt = 0; nt < 2; ++nt) {
        int dim = h * 32 + nt * 16 + c0;
        bf16x8 b0 = *(const bf16x8*)(vt + (size_t)dim * PH + quad * 8);
        bf16x8 b1v = *(const bf16x8*)(vt + (size_t)dim * PH + 32 + quad * 8);
        f32x4 acc = {0.f, 0.f, 0.f, 0.f};
        acc = __builtin_amdgcn_mfma_f32_16x16x32_bf16(a0, b0, acc, 0, 0, 0);
        acc = __builtin_amdgcn_mfma_f32_16x16x32_bf16(a1, b1v, acc, 0, 0, 0);
#pragma unroll
        for (int r = 0; r < 4; ++r)
          qh[(mt * 16 + quad * 4 + r) * PH + dim] = f2b(acc[r]);
      }
    }
    __syncthreads();

    // ---- O-projection + residual + LN1 -> xh
    {
      f32x4 o4[4];
      mm64(qh, Wo, arow, quad, lane, o4);
      ln_epilogue(o4, xh, ln1g + blk * SD, ln1b + blk * SD, nullptr, mt, quad, c0);
    }
    __syncthreads();

    // ---- FFN: 4 chunks of 64 hidden dims; h -> qh; W2 accumulates in regs
    f32x4 facc[4];
#pragma unroll
    for (int nt = 0; nt < 4; ++nt) facc[nt] = (f32x4){0.f, 0.f, 0.f, 0.f};
#pragma unroll 1
    for (int c = 0; c < 4; ++c) {
      {
        bf16x8 a0 = *(const bf16x8*)(xh + arow * PH + quad * 8);
        bf16x8 a1 = *(const bf16x8*)(xh + arow * PH + 32 + quad * 8);
#pragma unroll
        for (int nt = 0; nt < 4; ++nt) {
          int ntg = c * 4 + nt;
          f32x4 acc = {0.f, 0.f, 0.f, 0.f};
          acc = __builtin_amdgcn_mfma_f32_16x16x32_bf16(a0, ldB(W1, 0 * 16 + ntg, lane), acc, 0, 0, 0);
          acc = __builtin_amdgcn_mfma_f32_16x16x32_bf16(a1, ldB(W1, 1 * 16 + ntg, lane), acc, 0, 0, 0);
          int cc = nt * 16 + c0;
          float b1v = b1[blk * 256 + c * 64 + cc];
#pragma unroll
          for (int r = 0; r < 4; ++r)
            qh[(mt * 16 + quad * 4 + r) * PH + cc] = f2b(gelu_tanh(acc[r] + b1v));
        }
      }
      __syncthreads();
      {
        bf16x8 a0 = *(const bf16x8*)(qh + arow * PH + quad * 8);
        bf16x8 a1 = *(const bf16x8*)(qh + arow * PH + 32 + quad * 8);
#pragma unroll
        for (int nt = 0; nt < 4; ++nt) {
          facc[nt] = __builtin_amdgcn_mfma_f32_16x16x32_bf16(a0, ldB(W2, (2 * c) * 4 + nt, lane), facc[nt], 0, 0, 0);
          facc[nt] = __builtin_amdgcn_mfma_f32_16x16x32_bf16(a1, ldB(W2, (2 * c + 1) * 4 + nt, lane), facc[nt], 0, 0, 0);
        }
      }
      __syncthreads();
    }

    // ---- residual + b2 + LN2 -> xh
    ln_epilogue(facc, xh, ln2g + blk * SD, ln2b + blk * SD, b2 + blk * SD, mt, quad, c0);
    __syncthreads();
  }

  // ---- final LN + gather row (lengths-1)
  if (mt == 0) {
    int sl = len - 1;
    float val = b2f(xh[sl * PH + lane]);
    float2 ss = wred_sum2(val, val * val);
    float m = ss.x * (1.f / 64);
    float var = fmaxf(ss.y * (1.f / 64) - m * m, 0.f);
    float rs = rsqrtf(var + 1e-5f);
    out[b * SD + lane] = (val - m) * rs * lnfg[lane] + lnfb[lane];
  }
}

// ---------------------------------------------------------------------------
extern "C" void kernel_launch(void* const* d_in, const int* in_sizes, int n_in,
                              void* d_out, int out_size, void* d_ws, size_t ws_size,
                              hipStream_t stream) {
  const int*   seq   = (const int*)d_in[0];
  const int*   lens  = (const int*)d_in[1];
  const int*   ei    = (const int*)d_in[2];
  const float* ew    = (const float*)d_in[3];
  const float* bert  = (const float*)d_in[4];
  const float* gnn   = (const float*)d_in[5];
  const float* pw    = (const float*)d_in[6];
  const float* pb    = (const float*)d_in[7];
  const float* pos   = (const float*)d_in[8];
  const float* wq    = (const float*)d_in[9];
  const float* wk    = (const float*)d_in[10];
  const float* wv    = (const float*)d_in[11];
  const float* wo    = (const float*)d_in[12];
  const float* w1    = (const float*)d_in[13];
  const float* b1    = (const float*)d_in[14];
  const float* w2    = (const float*)d_in[15];
  const float* b2    = (const float*)d_in[16];
  const float* ln1g  = (const float*)d_in[17];
  const float* ln1b  = (const float*)d_in[18];
  const float* ln2g  = (const float*)d_in[19];
  const float* ln2b  = (const float*)d_in[20];
  const float* lnfg  = (const float*)d_in[21];
  const float* lnfb  = (const float*)d_in[22];
  float* out = (float*)d_out;

  const int E = in_sizes[2] / 2;          // 1,000,000
  const int B = in_sizes[0] / SS;         // 1024
  const int N = in_sizes[4] / SD;         // 100,001

  const int* esrc = ei;
  const int* edst = ei + E;

  // ---- workspace layout: bf16 B-frag weights first (204,800 B), then GNN.
  short* pwB = (short*)d_ws;              // 1*2*4*64*8   = 4096 halves
  short* wqB = pwB + 4096;                // 2*2*4*64*8   = 8192
  short* wkB = wqB + 8192;
  short* wvB = wkB + 8192;
  short* woB = wvB + 8192;
  short* w1B = woB + 8192;                // 2*2*16*64*8  = 32768
  short* w2B = w1B + 32768;               // 2*8*4*64*8   = 32768
  float* g1x = (float*)(w2B + 32768);     // byte offset 204,800 (16B-aligned)
  float* g2x = g1x + (size_t)N * SD;
  const int NCH = (N + 1023) >> 10;
  const int PADN = NCH << 10;
  int*   cnt  = (int*)(g2x + (size_t)N * SD);
  int*   bsum = cnt + PADN;
  int*   rp   = bsum + 128;
  int*   wp   = rp + (N + 1);
  int*   es   = wp + N;
  float* ewt  = (float*)(es + E);
  size_t need = (size_t)((char*)(ewt + E) - (char*)d_ws);

  // ---- weight prep (tiny; L2-resident outputs)
  prep_b<<<2, 256, 0, stream>>>(pw, 64, 64, 1, pwB);
  prep_b<<<4, 256, 0, stream>>>(wq, 64, 64, 2, wqB);
  prep_b<<<4, 256, 0, stream>>>(wk, 64, 64, 2, wkB);
  prep_b<<<4, 256, 0, stream>>>(wv, 64, 64, 2, wvB);
  prep_b<<<4, 256, 0, stream>>>(wo, 64, 64, 2, woB);
  prep_b<<<16, 256, 0, stream>>>(w1, 64, 256, 2, w1B);
  prep_b<<<16, 256, 0, stream>>>(w2, 256, 64, 2, w2B);

  if (ws_size >= need && NCH <= 128) {
    // ---- CSR build + gather (no atomics in the heavy passes)
    hipMemsetAsync(cnt, 0, (size_t)PADN * sizeof(int), stream);
    const int gb = (E + 255) / 256;
    gnn_hist<<<gb, 256, 0, stream>>>(edst, cnt, E);
    gnn_chunk_sums<<<NCH, 256, 0, stream>>>(cnt, bsum);
    gnn_scan_bsum<<<1, 128, 0, stream>>>(bsum, NCH);
    gnn_chunk_scan<<<NCH, 256, 0, stream>>>(cnt, bsum, rp, wp, N);
    gnn_build<<<gb, 256, 0, stream>>>(esrc, edst, ew, wp, es, ewt, E);
    const int nb = (N + 3) / 4;
    gnn_gather<<<nb, 256, 0, stream>>>(gnn, rp, es, ewt, g1x, N);
    gnn_gather<<<nb, 256, 0, stream>>>(g1x, rp, es, ewt, g2x, N);
  } else {
    // ---- fallback: atomic scatter
    hipMemsetAsync(g1x, 0, (size_t)2 * N * SD * sizeof(float), stream);
    const long total = (long)E * 64;
    const int sblocks = (int)((total + 255) / 256);
    gnn_scatter<<<sblocks, 256, 0, stream>>>(gnn, esrc, edst, ew, g1x, E);
    gnn_scatter<<<sblocks, 256, 0, stream>>>(g1x, esrc, edst, ew, g2x, E);
  }

  seq_transformer<<<B, 256, 0, stream>>>(
      seq, lens, bert, gnn, g1x, g2x, pb, pos,
      pwB, wqB, wkB, wvB, woB, w1B, w2B,
      b1, b2, ln1g, ln1b, ln2g, ln2b, lnfg, lnfb, out);
}

// Round 10
// 472.264 us; speedup vs baseline: 1.8635x; 1.0700x over previous
//
#include <hip/hip_runtime.h>
#include <math.h>

// ---------------------------------------------------------------------------
// HybridBERT4RecGNN forward on MI355X (gfx950), round 10.
//
// R9: MFMA transformer landed (~165 us). Bottleneck moved to GNN+prep
// (~340 us). R10: (a) bf16 node tables for the gather-SpMV passes (random
// row 256->128 B), (b) gather2 fuses the (gnn+x1+x2)/3 average into one bf16
// table read by the transformer (3 random tables -> 1), (c) packed int2
// edges (1x8B random store/load instead of 2x4B), (d) 32 lanes/node gathers,
// (e) 7 weight-prep launches -> 1.
// ---------------------------------------------------------------------------

typedef __attribute__((ext_vector_type(8))) short bf16x8;
typedef __attribute__((ext_vector_type(4))) float f32x4;

#define SD   64
#define SS   50
#define NBLK 2
#define PH   72    // LDS pitch in halves (144 B, 16B-aligned, bank-friendly)

__device__ __forceinline__ short f2b(float f) {  // fp32 -> bf16 RNE
  union { float f; unsigned u; } v; v.f = f;
  unsigned r = v.u + 0x7FFFu + ((v.u >> 16) & 1u);
  return (short)(r >> 16);
}
__device__ __forceinline__ float b2f(short s) {
  union { unsigned u; float f; } v;
  v.u = ((unsigned)(unsigned short)s) << 16;
  return v.f;
}
__device__ __forceinline__ unsigned packb(float a, float b) {
  return ((unsigned)(unsigned short)f2b(a)) | (((unsigned)(unsigned short)f2b(b)) << 16);
}
__device__ __forceinline__ float wred_sum(float v) {
#pragma unroll
  for (int o = 32; o > 0; o >>= 1) v += __shfl_xor(v, o, 64);
  return v;
}
__device__ __forceinline__ float wred_max(float v) {
#pragma unroll
  for (int o = 32; o > 0; o >>= 1) v = fmaxf(v, __shfl_xor(v, o, 64));
  return v;
}
__device__ __forceinline__ float2 wred_sum2(float a, float b) {
#pragma unroll
  for (int o = 32; o > 0; o >>= 1) {
    a += __shfl_xor(a, o, 64);
    b += __shfl_xor(b, o, 64);
  }
  return make_float2(a, b);
}
__device__ __forceinline__ float gelu_tanh(float x) {
  float u = 0.7978845608028654f * (x + 0.044715f * x * x * x);
  float a = fabsf(u);
  float e = __expf(-2.f * a);
  float th = copysignf((1.f - e) / (1.f + e), u);
  return 0.5f * x * (1.0f + th);
}

__device__ __forceinline__ bf16x8 ldB(const short* __restrict__ Wb, int tile, int lane) {
  return *(const bf16x8*)(Wb + ((size_t)tile * 64 + lane) * 8);
}

__device__ __forceinline__ void mm64(const short* A, const short* __restrict__ Wb,
                                     int arow, int quad, int lane, f32x4 o4[4]) {
  bf16x8 a0 = *(const bf16x8*)(A + arow * PH + quad * 8);
  bf16x8 a1 = *(const bf16x8*)(A + arow * PH + 32 + quad * 8);
#pragma unroll
  for (int nt = 0; nt < 4; ++nt) {
    f32x4 acc = {0.f, 0.f, 0.f, 0.f};
    acc = __builtin_amdgcn_mfma_f32_16x16x32_bf16(a0, ldB(Wb, 0 * 4 + nt, lane), acc, 0, 0, 0);
    acc = __builtin_amdgcn_mfma_f32_16x16x32_bf16(a1, ldB(Wb, 1 * 4 + nt, lane), acc, 0, 0, 0);
    o4[nt] = acc;
  }
}

__device__ __forceinline__ void ln_epilogue(f32x4 o4[4], short* xh,
                                            const float* __restrict__ g,
                                            const float* __restrict__ bta,
                                            const float* __restrict__ extrab,
                                            int mt, int quad, int c0) {
  float vals[4][4];
  float s1[4] = {0.f, 0.f, 0.f, 0.f}, s2[4] = {0.f, 0.f, 0.f, 0.f};
#pragma unroll
  for (int nt = 0; nt < 4; ++nt) {
    int c = nt * 16 + c0;
    float eb = extrab ? extrab[c] : 0.f;
#pragma unroll
    for (int r = 0; r < 4; ++r) {
      int row = mt * 16 + quad * 4 + r;
      float v = o4[nt][r] + b2f(xh[row * PH + c]) + eb;
      vals[nt][r] = v;
      s1[r] += v;
      s2[r] += v * v;
    }
  }
#pragma unroll
  for (int o = 1; o < 16; o <<= 1) {
#pragma unroll
    for (int r = 0; r < 4; ++r) {
      s1[r] += __shfl_xor(s1[r], o, 64);
      s2[r] += __shfl_xor(s2[r], o, 64);
    }
  }
  float mv[4], rv[4];
#pragma unroll
  for (int r = 0; r < 4; ++r) {
    float m = s1[r] * (1.f / 64);
    float var = fmaxf(s2[r] * (1.f / 64) - m * m, 0.f);
    mv[r] = m;
    rv[r] = rsqrtf(var + 1e-5f);
  }
#pragma unroll
  for (int nt = 0; nt < 4; ++nt) {
    int c = nt * 16 + c0;
    float gv = g[c], bv = bta[c];
#pragma unroll
    for (int r = 0; r < 4; ++r) {
      int row = mt * 16 + quad * 4 + r;
      xh[row * PH + c] = f2b((vals[nt][r] - mv[r]) * rv[r] * gv + bv);
    }
  }
}

// ---------------------------------------------------------------------------
// Combined weight prep: all 7 matrices -> bf16 B-frag tiles in one launch.
// Tile order within a matrix: tile = (m*KT+kt)*NT+nt, nt fastest.
// Global tile ranges: pw[0,8) wq[8,24) wk[24,40) wv[40,56) wo[56,72)
//                     w1[72,136) w2[136,200).  Grid: 200*64/256 = 50 blocks.
// ---------------------------------------------------------------------------
__global__ void prep_all(const float* __restrict__ pw, const float* __restrict__ wq,
                         const float* __restrict__ wk, const float* __restrict__ wv,
                         const float* __restrict__ wo, const float* __restrict__ w1,
                         const float* __restrict__ w2,
                         short* __restrict__ pwB, short* __restrict__ wqB,
                         short* __restrict__ wkB, short* __restrict__ wvB,
                         short* __restrict__ woB, short* __restrict__ w1B,
                         short* __restrict__ w2B) {
  int tid = blockIdx.x * blockDim.x + threadIdx.x;
  int lane = tid & 63;
  int tile = tid >> 6;
  const float* W; short* out; int K, N, base;
  if (tile < 8)        { W = pw; out = pwB; K = 64;  N = 64;  base = 0; }
  else if (tile < 24)  { W = wq; out = wqB; K = 64;  N = 64;  base = 8; }
  else if (tile < 40)  { W = wk; out = wkB; K = 64;  N = 64;  base = 24; }
  else if (tile < 56)  { W = wv; out = wvB; K = 64;  N = 64;  base = 40; }
  else if (tile < 72)  { W = wo; out = woB; K = 64;  N = 64;  base = 56; }
  else if (tile < 136) { W = w1; out = w1B; K = 64;  N = 256; base = 72; }
  else if (tile < 200) { W = w2; out = w2B; K = 256; N = 64;  base = 136; }
  else return;
  int lt = tile - base;
  int KT = K / 32, NT = N / 16;
  int nt = lt % NT; lt /= NT;
  int kt = lt % KT; lt /= KT;
  int m = lt;
  const float* Wm = W + (size_t)m * K * N;
  int kbase = kt * 32 + ((lane >> 4) * 8);
  int n = nt * 16 + (lane & 15);
  short v[8];
#pragma unroll
  for (int j = 0; j < 8; ++j) v[j] = f2b(Wm[(size_t)(kbase + j) * N + n]);
  *(bf16x8*)(out + ((size_t)(tile - base) * 64 + lane) * 8) = *(bf16x8*)v;
}

// fp32 table -> packed-bf16 table (pairs)
__global__ void cvt_bf16(const float* __restrict__ in, unsigned* __restrict__ out, int n32) {
  int i = blockIdx.x * blockDim.x + threadIdx.x;
  if (i >= n32) return;
  float2 f = ((const float2*)in)[i];
  out[i] = packb(f.x, f.y);
}

// ---------------------------------------------------------------------------
// GNN CSR build
// ---------------------------------------------------------------------------
__global__ void gnn_hist(const int* __restrict__ dst, int* __restrict__ cnt, int E) {
  int e = blockIdx.x * blockDim.x + threadIdx.x;
  if (e < E) atomicAdd(&cnt[dst[e]], 1);
}

__global__ void gnn_chunk_sums(const int* __restrict__ cnt, int* __restrict__ bsum) {
  __shared__ int ssum;
  if (threadIdx.x == 0) ssum = 0;
  __syncthreads();
  int base = blockIdx.x * 1024 + threadIdx.x * 4;
  int s = cnt[base] + cnt[base + 1] + cnt[base + 2] + cnt[base + 3];
#pragma unroll
  for (int o = 32; o > 0; o >>= 1) s += __shfl_xor(s, o, 64);
  if ((threadIdx.x & 63) == 0) atomicAdd(&ssum, s);
  __syncthreads();
  if (threadIdx.x == 0) bsum[blockIdx.x] = ssum;
}

__global__ void gnn_scan_bsum(int* __restrict__ bsum, int nch) {
  __shared__ int sb[128];
  int t = threadIdx.x;
  if (t < nch) sb[t] = bsum[t];
  __syncthreads();
  if (t == 0) {
    int a = 0;
    for (int i = 0; i < nch; ++i) { int v = sb[i]; sb[i] = a; a += v; }
  }
  __syncthreads();
  if (t < nch) bsum[t] = sb[t];
}

__global__ void gnn_chunk_scan(const int* __restrict__ cnt, const int* __restrict__ bofs,
                               int* __restrict__ rp, int* __restrict__ wp, int Nn) {
  __shared__ int wsum[4];
  int t = threadIdx.x, lane = t & 63, wv = t >> 6;
  int base = blockIdx.x * 1024 + t * 4;
  int c0 = cnt[base], c1 = cnt[base + 1], c2 = cnt[base + 2], c3 = cnt[base + 3];
  int s = c0 + c1 + c2 + c3;
  int x = s;
#pragma unroll
  for (int o = 1; o < 64; o <<= 1) {
    int y = __shfl_up(x, o, 64);
    if (lane >= o) x += y;
  }
  if (lane == 63) wsum[wv] = x;
  __syncthreads();
  int wo = 0;
#pragma unroll
  for (int i = 0; i < 4; ++i) if (i < wv) wo += wsum[i];
  int excl = bofs[blockIdx.x] + wo + (x - s);
  int p[4];
  p[0] = excl; p[1] = p[0] + c0; p[2] = p[1] + c1; p[3] = p[2] + c2;
#pragma unroll
  for (int j = 0; j < 4; ++j) {
    int idx = base + j;
    if (idx <= Nn) rp[idx] = p[j];
    if (idx < Nn) wp[idx] = p[j];
  }
}

__global__ void gnn_build(const int* __restrict__ src, const int* __restrict__ dst,
                          const float* __restrict__ ew, int* __restrict__ wp,
                          int2* __restrict__ ep, int E) {
  int e = blockIdx.x * blockDim.x + threadIdx.x;
  if (e >= E) return;
  int pos = atomicAdd(&wp[dst[e]], 1);
  ep[pos] = make_int2(src[e], __float_as_int(ew[e]));
}

// ---------------------------------------------------------------------------
// Gather layer 1: x1 = A @ bf16(gnn).  32 lanes per node (2 nodes/wave),
// lane handles a packed bf16 dim-pair; fp32 accumulate; bf16 out.
// ---------------------------------------------------------------------------
__global__ void gnn_gather1(const unsigned* __restrict__ xinh,
                            const int* __restrict__ rp, const int2* __restrict__ ep,
                            unsigned* __restrict__ xouth, int Nn) {
  int n = blockIdx.x * 8 + (threadIdx.x >> 5);
  int hl = threadIdx.x & 31;
  if (n >= Nn) return;
  int beg = rp[n], end = rp[n + 1];
  float a0 = 0.f, a1 = 0.f;
  int e = beg;
  for (; e + 2 <= end; e += 2) {
    int2 e0 = ep[e], e1 = ep[e + 1];
    float w0 = __int_as_float(e0.y), w1 = __int_as_float(e1.y);
    unsigned p0 = xinh[(size_t)e0.x * 32 + hl];
    unsigned p1 = xinh[(size_t)e1.x * 32 + hl];
    a0 += b2f((short)(p0 & 0xFFFF)) * w0 + b2f((short)(p1 & 0xFFFF)) * w1;
    a1 += b2f((short)(p0 >> 16)) * w0 + b2f((short)(p1 >> 16)) * w1;
  }
  for (; e < end; ++e) {
    int2 ee = ep[e];
    float w = __int_as_float(ee.y);
    unsigned p = xinh[(size_t)ee.x * 32 + hl];
    a0 += b2f((short)(p & 0xFFFF)) * w;
    a1 += b2f((short)(p >> 16)) * w;
  }
  xouth[(size_t)n * 32 + hl] = packb(a0, a1);
}

// ---------------------------------------------------------------------------
// Gather layer 2 + fused LightGCN average:
//   x2[n] = A @ x1 (bf16 neighbor reads);  avg[n] = (gnn[n]+x1[n]+x2[n])/3.
// ---------------------------------------------------------------------------
__global__ void gnn_gather_avg(const unsigned* __restrict__ x1h,
                               const int* __restrict__ rp, const int2* __restrict__ ep,
                               const float* __restrict__ gnn,
                               unsigned* __restrict__ avgh, int Nn) {
  int n = blockIdx.x * 8 + (threadIdx.x >> 5);
  int hl = threadIdx.x & 31;
  if (n >= Nn) return;
  int beg = rp[n], end = rp[n + 1];
  float a0 = 0.f, a1 = 0.f;
  int e = beg;
  for (; e + 2 <= end; e += 2) {
    int2 e0 = ep[e], e1 = ep[e + 1];
    float w0 = __int_as_float(e0.y), w1 = __int_as_float(e1.y);
    unsigned p0 = x1h[(size_t)e0.x * 32 + hl];
    unsigned p1 = x1h[(size_t)e1.x * 32 + hl];
    a0 += b2f((short)(p0 & 0xFFFF)) * w0 + b2f((short)(p1 & 0xFFFF)) * w1;
    a1 += b2f((short)(p0 >> 16)) * w0 + b2f((short)(p1 >> 16)) * w1;
  }
  for (; e < end; ++e) {
    int2 ee = ep[e];
    float w = __int_as_float(ee.y);
    unsigned p = x1h[(size_t)ee.x * 32 + hl];
    a0 += b2f((short)(p & 0xFFFF)) * w;
    a1 += b2f((short)(p >> 16)) * w;
  }
  float2 g = ((const float2*)gnn)[(size_t)n * 32 + hl];
  unsigned own = x1h[(size_t)n * 32 + hl];
  float v0 = (g.x + b2f((short)(own & 0xFFFF)) + a0) * (1.f / 3.f);
  float v1 = (g.y + b2f((short)(own >> 16)) + a1) * (1.f / 3.f);
  avgh[(size_t)n * 32 + hl] = packb(v0, v1);
}

// fallback helpers (fp32 scatter path)
__global__ void gnn_scatter(const float* __restrict__ xin,
                            const int* __restrict__ src,
                            const int* __restrict__ dst,
                            const float* __restrict__ ew,
                            float* __restrict__ xout, int E) {
  int gid = blockIdx.x * blockDim.x + threadIdx.x;
  int e = gid >> 6;
  int d = gid & 63;
  if (e >= E) return;
  atomicAdd(&xout[(size_t)dst[e] * SD + d], xin[(size_t)src[e] * SD + d] * ew[e]);
}
__global__ void avg_from_f32(const float* __restrict__ gnn, const float* __restrict__ g1,
                             const float* __restrict__ g2, unsigned* __restrict__ avgh,
                             int n32) {
  int i = blockIdx.x * blockDim.x + threadIdx.x;
  if (i >= n32) return;
  float2 a = ((const float2*)gnn)[i];
  float2 b = ((const float2*)g1)[i];
  float2 c = ((const float2*)g2)[i];
  avgh[i] = packb((a.x + b.x + c.x) * (1.f / 3.f), (a.y + b.y + c.y) * (1.f / 3.f));
}

// ---------------------------------------------------------------------------
// MFMA transformer: 256 threads = 4 waves; wave = mt (row-tile 0..3).
// LDS 46,336 B.  avgh: single bf16 fused-GNN table (replaces 3 fp32 tables).
// ---------------------------------------------------------------------------
__global__ __launch_bounds__(256, 6)
void seq_transformer(const int* __restrict__ seq, const int* __restrict__ lengths,
                     const float* __restrict__ bert, const short* __restrict__ avgh,
                     const float* __restrict__ pbias, const float* __restrict__ pos,
                     const short* __restrict__ pwB, const short* __restrict__ wqB,
                     const short* __restrict__ wkB, const short* __restrict__ wvB,
                     const short* __restrict__ woB, const short* __restrict__ w1B,
                     const short* __restrict__ w2B,
                     const float* __restrict__ b1, const float* __restrict__ b2,
                     const float* __restrict__ ln1g, const float* __restrict__ ln1b,
                     const float* __restrict__ ln2g, const float* __restrict__ ln2b,
                     const float* __restrict__ lnfg, const float* __restrict__ lnfb,
                     float* __restrict__ out) {
  __shared__ short xh[64 * PH];
  __shared__ short qh[64 * PH];
  __shared__ short kh[64 * PH];
  __shared__ short vt[64 * PH];
  __shared__ short s0[64 * PH];
  __shared__ int   sidx[64];

  const int t = threadIdx.x;
  const int lane = t & 63;
  const int mt = t >> 6;
  const int quad = lane >> 4;
  const int c0 = lane & 15;
  const int b = blockIdx.x;
  const int arow = mt * 16 + c0;

  if (t < 64) sidx[t] = (t < SS) ? seq[b * SS + t] : 0;
  __syncthreads();

  const int len = lengths[b];
  const float alpha = (len <= 10) ? 0.3f : ((len >= 50) ? 0.7f : 0.5f);
  const float isq = 0.17677669529663687f;  // 1/sqrt(32)

  // ---- phase 0a: fused GNN-average rows (bf16, single table) -> qh
#pragma unroll
  for (int ir = 0; ir < 16; ++ir) {
    int s = mt + 4 * ir;
    short v = 0;
    if (s < SS) v = avgh[(size_t)sidx[s] * SD + lane];
    qh[s * PH + lane] = v;
  }
  __syncthreads();

  // ---- phase 0b: gnn projection (MFMA) + blend + pos -> xh
  {
    f32x4 o4[4];
    mm64(qh, pwB, arow, quad, lane, o4);
#pragma unroll
    for (int nt = 0; nt < 4; ++nt) {
      int c = nt * 16 + c0;
      float pbv = pbias[c];
#pragma unroll
      for (int r = 0; r < 4; ++r) {
        int row = mt * 16 + quad * 4 + r;
        short ov = 0;
        if (row < SS) {
          float g = o4[nt][r] + pbv;
          float xv = alpha * bert[(size_t)sidx[row] * SD + c] +
                     (1.f - alpha) * g + pos[row * SD + c];
          ov = f2b(xv);
        }
        xh[row * PH + c] = ov;
      }
    }
  }
  __syncthreads();

#pragma unroll 1
  for (int blk = 0; blk < NBLK; ++blk) {
    const short* Wq = wqB + blk * 4096;
    const short* Wk = wkB + blk * 4096;
    const short* Wv = wvB + blk * 4096;
    const short* Wo = woB + blk * 4096;
    const short* W1 = w1B + blk * 16384;
    const short* W2 = w2B + blk * 16384;

    // ---- Q -> qh, K -> kh (row-major), V -> vt (transposed)
    {
      f32x4 o4[4];
      mm64(xh, Wq, arow, quad, lane, o4);
#pragma unroll
      for (int nt = 0; nt < 4; ++nt) {
        int c = nt * 16 + c0;
#pragma unroll
        for (int r = 0; r < 4; ++r) qh[(mt * 16 + quad * 4 + r) * PH + c] = f2b(o4[nt][r]);
      }
      mm64(xh, Wk, arow, quad, lane, o4);
#pragma unroll
      for (int nt = 0; nt < 4; ++nt) {
        int c = nt * 16 + c0;
#pragma unroll
        for (int r = 0; r < 4; ++r) kh[(mt * 16 + quad * 4 + r) * PH + c] = f2b(o4[nt][r]);
      }
      mm64(xh, Wv, arow, quad, lane, o4);
#pragma unroll
      for (int nt = 0; nt < 4; ++nt) {
        int dim = nt * 16 + c0;
        unsigned p0 = packb(o4[nt][0], o4[nt][1]);
        unsigned p1 = packb(o4[nt][2], o4[nt][3]);
        *(uint2*)(vt + (size_t)dim * PH + mt * 16 + quad * 4) = make_uint2(p0, p1);
      }
    }
    __syncthreads();

    // ---- scores: S_h = Q_h K_h^T
    {
      bf16x8 aq0 = *(const bf16x8*)(qh + arow * PH + quad * 8);
      bf16x8 aq1 = *(const bf16x8*)(qh + arow * PH + 32 + quad * 8);
      f32x4 sa1[4];
#pragma unroll
      for (int nt = 0; nt < 4; ++nt) {
        int key = nt * 16 + c0;
        bf16x8 bk0 = *(const bf16x8*)(kh + key * PH + quad * 8);
        f32x4 acc = {0.f, 0.f, 0.f, 0.f};
        acc = __builtin_amdgcn_mfma_f32_16x16x32_bf16(aq0, bk0, acc, 0, 0, 0);
        bool km = (key < SS) && (sidx[key] != 0);
#pragma unroll
        for (int r = 0; r < 4; ++r) {
          int q = mt * 16 + quad * 4 + r;
          s0[q * PH + key] = f2b(km ? acc[r] * isq : -1e9f);
        }
        bf16x8 bk1 = *(const bf16x8*)(kh + key * PH + 32 + quad * 8);
        f32x4 acc1 = {0.f, 0.f, 0.f, 0.f};
        sa1[nt] = __builtin_amdgcn_mfma_f32_16x16x32_bf16(aq1, bk1, acc1, 0, 0, 0);
      }
      __syncthreads();  // all waves done reading kh
#pragma unroll
      for (int nt = 0; nt < 4; ++nt) {
        int key = nt * 16 + c0;
        bool km = (key < SS) && (sidx[key] != 0);
#pragma unroll
        for (int r = 0; r < 4; ++r) {
          int q = mt * 16 + quad * 4 + r;
          kh[q * PH + key] = f2b(km ? sa1[nt][r] * isq : -1e9f);
        }
      }
    }
    __syncthreads();

    // ---- softmax: 100 rows over 4 waves; P cols 50-63 forced to 0
#pragma unroll 1
    for (int i = mt; i < 2 * SS; i += 4) {
      short* buf = (i < SS) ? s0 : kh;
      int r = (i < SS) ? i : i - SS;
      float v = (lane < SS) ? b2f(buf[r * PH + lane]) : -1e30f;
      float mx = wred_max(v);
      float e = (lane < SS) ? __expf(v - mx) : 0.f;
      float sm = wred_sum(e);
      buf[r * PH + lane] = f2b(e / sm);
    }
    __syncthreads();

    // ---- ctx = P V -> qh
#pragma unroll
    for (int h = 0; h < 2; ++h) {
      const short* P = h ? kh : s0;
      bf16x8 a0 = *(const bf16x8*)(P + arow * PH + quad * 8);
      bf16x8 a1 = *(const bf16x8*)(P + arow * PH + 32 + quad * 8);
#pragma unroll
      for (int nt = 0; nt < 2; ++nt) {
        int dim = h * 32 + nt * 16 + c0;
        bf16x8 b0 = *(const bf16x8*)(vt + (size_t)dim * PH + quad * 8);
        bf16x8 b1v = *(const bf16x8*)(vt + (size_t)dim * PH + 32 + quad * 8);
        f32x4 acc = {0.f, 0.f, 0.f, 0.f};
        acc = __builtin_amdgcn_mfma_f32_16x16x32_bf16(a0, b0, acc, 0, 0, 0);
        acc = __builtin_amdgcn_mfma_f32_16x16x32_bf16(a1, b1v, acc, 0, 0, 0);
#pragma unroll
        for (int r = 0; r < 4; ++r)
          qh[(mt * 16 + quad * 4 + r) * PH + dim] = f2b(acc[r]);
      }
    }
    __syncthreads();

    // ---- O-projection + residual + LN1 -> xh
    {
      f32x4 o4[4];
      mm64(qh, Wo, arow, quad, lane, o4);
      ln_epilogue(o4, xh, ln1g + blk * SD, ln1b + blk * SD, nullptr, mt, quad, c0);
    }
    __syncthreads();

    // ---- FFN
    f32x4 facc[4];
#pragma unroll
    for (int nt = 0; nt < 4; ++nt) facc[nt] = (f32x4){0.f, 0.f, 0.f, 0.f};
#pragma unroll 1
    for (int c = 0; c < 4; ++c) {
      {
        bf16x8 a0 = *(const bf16x8*)(xh + arow * PH + quad * 8);
        bf16x8 a1 = *(const bf16x8*)(xh + arow * PH + 32 + quad * 8);
#pragma unroll
        for (int nt = 0; nt < 4; ++nt) {
          int ntg = c * 4 + nt;
          f32x4 acc = {0.f, 0.f, 0.f, 0.f};
          acc = __builtin_amdgcn_mfma_f32_16x16x32_bf16(a0, ldB(W1, 0 * 16 + ntg, lane), acc, 0, 0, 0);
          acc = __builtin_amdgcn_mfma_f32_16x16x32_bf16(a1, ldB(W1, 1 * 16 + ntg, lane), acc, 0, 0, 0);
          int cc = nt * 16 + c0;
          float b1v = b1[blk * 256 + c * 64 + cc];
#pragma unroll
          for (int r = 0; r < 4; ++r)
            qh[(mt * 16 + quad * 4 + r) * PH + cc] = f2b(gelu_tanh(acc[r] + b1v));
        }
      }
      __syncthreads();
      {
        bf16x8 a0 = *(const bf16x8*)(qh + arow * PH + quad * 8);
        bf16x8 a1 = *(const bf16x8*)(qh + arow * PH + 32 + quad * 8);
#pragma unroll
        for (int nt = 0; nt < 4; ++nt) {
          facc[nt] = __builtin_amdgcn_mfma_f32_16x16x32_bf16(a0, ldB(W2, (2 * c) * 4 + nt, lane), facc[nt], 0, 0, 0);
          facc[nt] = __builtin_amdgcn_mfma_f32_16x16x32_bf16(a1, ldB(W2, (2 * c + 1) * 4 + nt, lane), facc[nt], 0, 0, 0);
        }
      }
      __syncthreads();
    }

    // ---- residual + b2 + LN2 -> xh
    ln_epilogue(facc, xh, ln2g + blk * SD, ln2b + blk * SD, b2 + blk * SD, mt, quad, c0);
    __syncthreads();
  }

  // ---- final LN + gather row (lengths-1)
  if (mt == 0) {
    int sl = len - 1;
    float val = b2f(xh[sl * PH + lane]);
    float2 ss = wred_sum2(val, val * val);
    float m = ss.x * (1.f / 64);
    float var = fmaxf(ss.y * (1.f / 64) - m * m, 0.f);
    float rs = rsqrtf(var + 1e-5f);
    out[b * SD + lane] = (val - m) * rs * lnfg[lane] + lnfb[lane];
  }
}

// ---------------------------------------------------------------------------
extern "C" void kernel_launch(void* const* d_in, const int* in_sizes, int n_in,
                              void* d_out, int out_size, void* d_ws, size_t ws_size,
                              hipStream_t stream) {
  const int*   seq   = (const int*)d_in[0];
  const int*   lens  = (const int*)d_in[1];
  const int*   ei    = (const int*)d_in[2];
  const float* ew    = (const float*)d_in[3];
  const float* bert  = (const float*)d_in[4];
  const float* gnn   = (const float*)d_in[5];
  const float* pw    = (const float*)d_in[6];
  const float* pb    = (const float*)d_in[7];
  const float* pos   = (const float*)d_in[8];
  const float* wq    = (const float*)d_in[9];
  const float* wk    = (const float*)d_in[10];
  const float* wv    = (const float*)d_in[11];
  const float* wo    = (const float*)d_in[12];
  const float* w1    = (const float*)d_in[13];
  const float* b1    = (const float*)d_in[14];
  const float* w2    = (const float*)d_in[15];
  const float* b2    = (const float*)d_in[16];
  const float* ln1g  = (const float*)d_in[17];
  const float* ln1b  = (const float*)d_in[18];
  const float* ln2g  = (const float*)d_in[19];
  const float* ln2b  = (const float*)d_in[20];
  const float* lnfg  = (const float*)d_in[21];
  const float* lnfb  = (const float*)d_in[22];
  float* out = (float*)d_out;

  const int E = in_sizes[2] / 2;          // 1,000,000
  const int B = in_sizes[0] / SS;         // 1024
  const int N = in_sizes[4] / SD;         // 100,001

  const int* esrc = ei;
  const int* edst = ei + E;

  // ---- workspace layout
  short* pwB = (short*)d_ws;              // 4096 halves
  short* wqB = pwB + 4096;                // 8192
  short* wkB = wqB + 8192;
  short* wvB = wkB + 8192;
  short* woB = wvB + 8192;
  short* w1B = woB + 8192;                // 32768
  short* w2B = w1B + 32768;               // 32768
  unsigned* gnnh = (unsigned*)(w2B + 32768);   // N*32 uints (bf16 pairs)
  unsigned* g1xh = gnnh + (size_t)N * 32;
  unsigned* avgh = g1xh + (size_t)N * 32;
  const int NCH = (N + 1023) >> 10;
  const int PADN = NCH << 10;
  int* cnt  = (int*)(avgh + (size_t)N * 32);
  int* bsum = cnt + PADN;
  int* rp   = bsum + 128;
  int* wp   = rp + (N + 1);
  // 8-byte align the packed edge array
  int2* ep = (int2*)((((size_t)(wp + N)) + 15) & ~(size_t)15);
  size_t need = (size_t)((char*)(ep + E) - (char*)d_ws);

  // fallback fp32 tables (overlay the CSR/scan region)
  float* g1x = (float*)cnt;
  float* g2x = g1x + (size_t)N * SD;
  size_t need_fb = (size_t)((char*)(g2x + (size_t)N * SD) - (char*)d_ws);

  // ---- weight prep (1 launch)
  prep_all<<<50, 256, 0, stream>>>(pw, wq, wk, wv, wo, w1, w2,
                                   pwB, wqB, wkB, wvB, woB, w1B, w2B);

  const int n32 = N * 32;
  if (ws_size >= need && NCH <= 128) {
    cvt_bf16<<<(n32 + 255) / 256, 256, 0, stream>>>(gnn, gnnh, n32);
    hipMemsetAsync(cnt, 0, (size_t)PADN * sizeof(int), stream);
    const int gb = (E + 255) / 256;
    gnn_hist<<<gb, 256, 0, stream>>>(edst, cnt, E);
    gnn_chunk_sums<<<NCH, 256, 0, stream>>>(cnt, bsum);
    gnn_scan_bsum<<<1, 128, 0, stream>>>(bsum, NCH);
    gnn_chunk_scan<<<NCH, 256, 0, stream>>>(cnt, bsum, rp, wp, N);
    gnn_build<<<gb, 256, 0, stream>>>(esrc, edst, ew, wp, ep, E);
    const int nb = (N + 7) / 8;
    gnn_gather1<<<nb, 256, 0, stream>>>(gnnh, rp, ep, g1xh, N);
    gnn_gather_avg<<<nb, 256, 0, stream>>>(g1xh, rp, ep, gnn, avgh, N);
  } else if (ws_size >= need_fb) {
    hipMemsetAsync(g1x, 0, (size_t)2 * N * SD * sizeof(float), stream);
    const long total = (long)E * 64;
    const int sblocks = (int)((total + 255) / 256);
    gnn_scatter<<<sblocks, 256, 0, stream>>>(gnn, esrc, edst, ew, g1x, E);
    gnn_scatter<<<sblocks, 256, 0, stream>>>(g1x, esrc, edst, ew, g2x, E);
    avg_from_f32<<<(n32 + 255) / 256, 256, 0, stream>>>(gnn, g1x, g2x, avgh, n32);
  }

  seq_transformer<<<B, 256, 0, stream>>>(
      seq, lens, bert, (const short*)avgh, pb, pos,
      pwB, wqB, wkB, wvB, woB, w1B, w2B,
      b1, b2, ln1g, ln1b, ln2g, ln2b, lnfg, lnfb, out);
}

// Round 11
// 432.854 us; speedup vs baseline: 2.0332x; 1.0910x over previous
//
#include <hip/hip_runtime.h>
#include <math.h>

// ---------------------------------------------------------------------------
// HybridBERT4RecGNN forward on MI355X (gfx950), round 11.
//
// R10: transformer stuck at ~160 us, MfmaUtil 3.9% -- barrier/latency bound
// (~30 __syncthreads per block serializing LDS round-trips vs L2 weight-load
// latency). R11: ROW-OWNERSHIP restructure. Wave mt owns rows [mt*16,mt*16+16)
// end-to-end: every MFMA stage reads A from own rows and writes D to own rows;
// softmax is row-owned (quad-split 16-lane butterflies); heads processed
// sequentially with ctx written into the consumed Q columns. Only cross-wave
// couplings left: K buffer + V^T buffer (scores/ctx read all rows) -> exactly
// 2 barriers per layer (+1 sidx, +1 final) = 6 total, down from ~30.
// Also: cvt_bf16 + gnn_hist fused (12 -> 10 dispatches).
// GNN CSR path otherwise unchanged from R10.
// ---------------------------------------------------------------------------

typedef __attribute__((ext_vector_type(8))) short bf16x8;
typedef __attribute__((ext_vector_type(4))) float f32x4;

#define SD   64
#define SS   50
#define NBLK 2
#define PH   72    // LDS pitch in halves (144 B, 16B-aligned rows, 2-way banks max)

__device__ __forceinline__ short f2b(float f) {  // fp32 -> bf16 RNE
  union { float f; unsigned u; } v; v.f = f;
  unsigned r = v.u + 0x7FFFu + ((v.u >> 16) & 1u);
  return (short)(r >> 16);
}
__device__ __forceinline__ float b2f(short s) {
  union { unsigned u; float f; } v;
  v.u = ((unsigned)(unsigned short)s) << 16;
  return v.f;
}
__device__ __forceinline__ unsigned packb(float a, float b) {
  return ((unsigned)(unsigned short)f2b(a)) | (((unsigned)(unsigned short)f2b(b)) << 16);
}
__device__ __forceinline__ float wred_sum(float v) {
#pragma unroll
  for (int o = 32; o > 0; o >>= 1) v += __shfl_xor(v, o, 64);
  return v;
}
__device__ __forceinline__ float2 wred_sum2(float a, float b) {
#pragma unroll
  for (int o = 32; o > 0; o >>= 1) {
    a += __shfl_xor(a, o, 64);
    b += __shfl_xor(b, o, 64);
  }
  return make_float2(a, b);
}
__device__ __forceinline__ float gelu_tanh(float x) {
  float u = 0.7978845608028654f * (x + 0.044715f * x * x * x);
  float a = fabsf(u);
  float e = __expf(-2.f * a);
  float th = copysignf((1.f - e) / (1.f + e), u);
  return 0.5f * x * (1.0f + th);
}

__device__ __forceinline__ bf16x8 ldB(const short* __restrict__ Wb, int tile, int lane) {
  return *(const bf16x8*)(Wb + ((size_t)tile * 64 + lane) * 8);
}

// [own 16 rows x K=64] @ [64x64] -> D own rows. A from LDS bf16 pitch PH.
__device__ __forceinline__ void mm64(const short* A, const short* __restrict__ Wb,
                                     int arow, int quad, int lane, f32x4 o4[4]) {
  bf16x8 a0 = *(const bf16x8*)(A + arow * PH + quad * 8);
  bf16x8 a1 = *(const bf16x8*)(A + arow * PH + 32 + quad * 8);
#pragma unroll
  for (int nt = 0; nt < 4; ++nt) {
    f32x4 acc = {0.f, 0.f, 0.f, 0.f};
    acc = __builtin_amdgcn_mfma_f32_16x16x32_bf16(a0, ldB(Wb, 0 * 4 + nt, lane), acc, 0, 0, 0);
    acc = __builtin_amdgcn_mfma_f32_16x16x32_bf16(a1, ldB(Wb, 1 * 4 + nt, lane), acc, 0, 0, 0);
    o4[nt] = acc;
  }
}

// LN over 64 cols of D-layout values + residual from xh + optional bias.
// Intra-wave only (16-lane quad butterflies).
__device__ __forceinline__ void ln_epilogue(f32x4 o4[4], short* xh,
                                            const float* __restrict__ g,
                                            const float* __restrict__ bta,
                                            const float* __restrict__ extrab,
                                            int mt, int quad, int c0) {
  float vals[4][4];
  float s1[4] = {0.f, 0.f, 0.f, 0.f}, s2[4] = {0.f, 0.f, 0.f, 0.f};
#pragma unroll
  for (int nt = 0; nt < 4; ++nt) {
    int c = nt * 16 + c0;
    float eb = extrab ? extrab[c] : 0.f;
#pragma unroll
    for (int r = 0; r < 4; ++r) {
      int row = mt * 16 + quad * 4 + r;
      float v = o4[nt][r] + b2f(xh[row * PH + c]) + eb;
      vals[nt][r] = v;
      s1[r] += v;
      s2[r] += v * v;
    }
  }
#pragma unroll
  for (int o = 1; o < 16; o <<= 1) {
#pragma unroll
    for (int r = 0; r < 4; ++r) {
      s1[r] += __shfl_xor(s1[r], o, 64);
      s2[r] += __shfl_xor(s2[r], o, 64);
    }
  }
  float mv[4], rv[4];
#pragma unroll
  for (int r = 0; r < 4; ++r) {
    float m = s1[r] * (1.f / 64);
    float var = fmaxf(s2[r] * (1.f / 64) - m * m, 0.f);
    mv[r] = m;
    rv[r] = rsqrtf(var + 1e-5f);
  }
#pragma unroll
  for (int nt = 0; nt < 4; ++nt) {
    int c = nt * 16 + c0;
    float gv = g[c], bv = bta[c];
#pragma unroll
    for (int r = 0; r < 4; ++r) {
      int row = mt * 16 + quad * 4 + r;
      xh[row * PH + c] = f2b((vals[nt][r] - mv[r]) * rv[r] * gv + bv);
    }
  }
}

// ---------------------------------------------------------------------------
// Combined weight prep (unchanged from R10)
// ---------------------------------------------------------------------------
__global__ void prep_all(const float* __restrict__ pw, const float* __restrict__ wq,
                         const float* __restrict__ wk, const float* __restrict__ wv,
                         const float* __restrict__ wo, const float* __restrict__ w1,
                         const float* __restrict__ w2,
                         short* __restrict__ pwB, short* __restrict__ wqB,
                         short* __restrict__ wkB, short* __restrict__ wvB,
                         short* __restrict__ woB, short* __restrict__ w1B,
                         short* __restrict__ w2B) {
  int tid = blockIdx.x * blockDim.x + threadIdx.x;
  int lane = tid & 63;
  int tile = tid >> 6;
  const float* W; short* out; int K, N, base;
  if (tile < 8)        { W = pw; out = pwB; K = 64;  N = 64;  base = 0; }
  else if (tile < 24)  { W = wq; out = wqB; K = 64;  N = 64;  base = 8; }
  else if (tile < 40)  { W = wk; out = wkB; K = 64;  N = 64;  base = 24; }
  else if (tile < 56)  { W = wv; out = wvB; K = 64;  N = 64;  base = 40; }
  else if (tile < 72)  { W = wo; out = woB; K = 64;  N = 64;  base = 56; }
  else if (tile < 136) { W = w1; out = w1B; K = 64;  N = 256; base = 72; }
  else if (tile < 200) { W = w2; out = w2B; K = 256; N = 64;  base = 136; }
  else return;
  int lt = tile - base;
  int KT = K / 32, NT = N / 16;
  int nt = lt % NT; lt /= NT;
  int kt = lt % KT; lt /= KT;
  int m = lt;
  const float* Wm = W + (size_t)m * K * N;
  int kbase = kt * 32 + ((lane >> 4) * 8);
  int n = nt * 16 + (lane & 15);
  short v[8];
#pragma unroll
  for (int j = 0; j < 8; ++j) v[j] = f2b(Wm[(size_t)(kbase + j) * N + n]);
  *(bf16x8*)(out + ((size_t)(tile - base) * 64 + lane) * 8) = *(bf16x8*)v;
}

// fp32 table -> packed bf16 pairs, fused with dst-degree histogram
__global__ void cvt_hist(const float* __restrict__ in, unsigned* __restrict__ out,
                         int n32, const int* __restrict__ dst, int* __restrict__ cnt,
                         int E) {
  int i = blockIdx.x * blockDim.x + threadIdx.x;
  if (i < n32) {
    float2 f = ((const float2*)in)[i];
    out[i] = packb(f.x, f.y);
  }
  if (i < E) atomicAdd(&cnt[dst[i]], 1);
}

// ---------------------------------------------------------------------------
// GNN CSR scan/build (unchanged from R10)
// ---------------------------------------------------------------------------
__global__ void gnn_chunk_sums(const int* __restrict__ cnt, int* __restrict__ bsum) {
  __shared__ int ssum;
  if (threadIdx.x == 0) ssum = 0;
  __syncthreads();
  int base = blockIdx.x * 1024 + threadIdx.x * 4;
  int s = cnt[base] + cnt[base + 1] + cnt[base + 2] + cnt[base + 3];
#pragma unroll
  for (int o = 32; o > 0; o >>= 1) s += __shfl_xor(s, o, 64);
  if ((threadIdx.x & 63) == 0) atomicAdd(&ssum, s);
  __syncthreads();
  if (threadIdx.x == 0) bsum[blockIdx.x] = ssum;
}

__global__ void gnn_scan_bsum(int* __restrict__ bsum, int nch) {
  __shared__ int sb[128];
  int t = threadIdx.x;
  if (t < nch) sb[t] = bsum[t];
  __syncthreads();
  if (t == 0) {
    int a = 0;
    for (int i = 0; i < nch; ++i) { int v = sb[i]; sb[i] = a; a += v; }
  }
  __syncthreads();
  if (t < nch) bsum[t] = sb[t];
}

__global__ void gnn_chunk_scan(const int* __restrict__ cnt, const int* __restrict__ bofs,
                               int* __restrict__ rp, int* __restrict__ wp, int Nn) {
  __shared__ int wsum[4];
  int t = threadIdx.x, lane = t & 63, wv = t >> 6;
  int base = blockIdx.x * 1024 + t * 4;
  int c0 = cnt[base], c1 = cnt[base + 1], c2 = cnt[base + 2], c3 = cnt[base + 3];
  int s = c0 + c1 + c2 + c3;
  int x = s;
#pragma unroll
  for (int o = 1; o < 64; o <<= 1) {
    int y = __shfl_up(x, o, 64);
    if (lane >= o) x += y;
  }
  if (lane == 63) wsum[wv] = x;
  __syncthreads();
  int wo = 0;
#pragma unroll
  for (int i = 0; i < 4; ++i) if (i < wv) wo += wsum[i];
  int excl = bofs[blockIdx.x] + wo + (x - s);
  int p[4];
  p[0] = excl; p[1] = p[0] + c0; p[2] = p[1] + c1; p[3] = p[2] + c2;
#pragma unroll
  for (int j = 0; j < 4; ++j) {
    int idx = base + j;
    if (idx <= Nn) rp[idx] = p[j];
    if (idx < Nn) wp[idx] = p[j];
  }
}

__global__ void gnn_build(const int* __restrict__ src, const int* __restrict__ dst,
                          const float* __restrict__ ew, int* __restrict__ wp,
                          int2* __restrict__ ep, int E) {
  int e = blockIdx.x * blockDim.x + threadIdx.x;
  if (e >= E) return;
  int pos = atomicAdd(&wp[dst[e]], 1);
  ep[pos] = make_int2(src[e], __float_as_int(ew[e]));
}

__global__ void gnn_gather1(const unsigned* __restrict__ xinh,
                            const int* __restrict__ rp, const int2* __restrict__ ep,
                            unsigned* __restrict__ xouth, int Nn) {
  int n = blockIdx.x * 8 + (threadIdx.x >> 5);
  int hl = threadIdx.x & 31;
  if (n >= Nn) return;
  int beg = rp[n], end = rp[n + 1];
  float a0 = 0.f, a1 = 0.f;
  int e = beg;
  for (; e + 2 <= end; e += 2) {
    int2 e0 = ep[e], e1 = ep[e + 1];
    float w0 = __int_as_float(e0.y), w1 = __int_as_float(e1.y);
    unsigned p0 = xinh[(size_t)e0.x * 32 + hl];
    unsigned p1 = xinh[(size_t)e1.x * 32 + hl];
    a0 += b2f((short)(p0 & 0xFFFF)) * w0 + b2f((short)(p1 & 0xFFFF)) * w1;
    a1 += b2f((short)(p0 >> 16)) * w0 + b2f((short)(p1 >> 16)) * w1;
  }
  for (; e < end; ++e) {
    int2 ee = ep[e];
    float w = __int_as_float(ee.y);
    unsigned p = xinh[(size_t)ee.x * 32 + hl];
    a0 += b2f((short)(p & 0xFFFF)) * w;
    a1 += b2f((short)(p >> 16)) * w;
  }
  xouth[(size_t)n * 32 + hl] = packb(a0, a1);
}

__global__ void gnn_gather_avg(const unsigned* __restrict__ x1h,
                               const int* __restrict__ rp, const int2* __restrict__ ep,
                               const float* __restrict__ gnn,
                               unsigned* __restrict__ avgh, int Nn) {
  int n = blockIdx.x * 8 + (threadIdx.x >> 5);
  int hl = threadIdx.x & 31;
  if (n >= Nn) return;
  int beg = rp[n], end = rp[n + 1];
  float a0 = 0.f, a1 = 0.f;
  int e = beg;
  for (; e + 2 <= end; e += 2) {
    int2 e0 = ep[e], e1 = ep[e + 1];
    float w0 = __int_as_float(e0.y), w1 = __int_as_float(e1.y);
    unsigned p0 = x1h[(size_t)e0.x * 32 + hl];
    unsigned p1 = x1h[(size_t)e1.x * 32 + hl];
    a0 += b2f((short)(p0 & 0xFFFF)) * w0 + b2f((short)(p1 & 0xFFFF)) * w1;
    a1 += b2f((short)(p0 >> 16)) * w0 + b2f((short)(p1 >> 16)) * w1;
  }
  for (; e < end; ++e) {
    int2 ee = ep[e];
    float w = __int_as_float(ee.y);
    unsigned p = x1h[(size_t)ee.x * 32 + hl];
    a0 += b2f((short)(p & 0xFFFF)) * w;
    a1 += b2f((short)(p >> 16)) * w;
  }
  float2 g = ((const float2*)gnn)[(size_t)n * 32 + hl];
  unsigned own = x1h[(size_t)n * 32 + hl];
  float v0 = (g.x + b2f((short)(own & 0xFFFF)) + a0) * (1.f / 3.f);
  float v1 = (g.y + b2f((short)(own >> 16)) + a1) * (1.f / 3.f);
  avgh[(size_t)n * 32 + hl] = packb(v0, v1);
}

// fallback helpers
__global__ void gnn_scatter(const float* __restrict__ xin,
                            const int* __restrict__ src,
                            const int* __restrict__ dst,
                            const float* __restrict__ ew,
                            float* __restrict__ xout, int E) {
  int gid = blockIdx.x * blockDim.x + threadIdx.x;
  int e = gid >> 6;
  int d = gid & 63;
  if (e >= E) return;
  atomicAdd(&xout[(size_t)dst[e] * SD + d], xin[(size_t)src[e] * SD + d] * ew[e]);
}
__global__ void avg_from_f32(const float* __restrict__ gnn, const float* __restrict__ g1,
                             const float* __restrict__ g2, unsigned* __restrict__ avgh,
                             int n32) {
  int i = blockIdx.x * blockDim.x + threadIdx.x;
  if (i >= n32) return;
  float2 a = ((const float2*)gnn)[i];
  float2 b = ((const float2*)g1)[i];
  float2 c = ((const float2*)g2)[i];
  avgh[i] = packb((a.x + b.x + c.x) * (1.f / 3.f), (a.y + b.y + c.y) * (1.f / 3.f));
}

// ---------------------------------------------------------------------------
// MFMA transformer, row-ownership version. 256 threads = 4 waves; wave mt
// owns rows [mt*16, mt*16+16) of every row-major buffer. Cross-wave data:
// kh (K, scores read all key rows) and vt (V^T, ctx reads all dim rows) ->
// 2 barriers/layer. Heads sequential; ctx_h overwrites Q cols h*32..h*32+31.
// LDS: 5 x 9216 + 256 = 46,336 B.
// ---------------------------------------------------------------------------
__global__ __launch_bounds__(256, 6)
void seq_transformer(const int* __restrict__ seq, const int* __restrict__ lengths,
                     const float* __restrict__ bert, const short* __restrict__ avgh,
                     const float* __restrict__ pbias, const float* __restrict__ pos,
                     const short* __restrict__ pwB, const short* __restrict__ wqB,
                     const short* __restrict__ wkB, const short* __restrict__ wvB,
                     const short* __restrict__ woB, const short* __restrict__ w1B,
                     const short* __restrict__ w2B,
                     const float* __restrict__ b1, const float* __restrict__ b2,
                     const float* __restrict__ ln1g, const float* __restrict__ ln1b,
                     const float* __restrict__ ln2g, const float* __restrict__ ln2b,
                     const float* __restrict__ lnfg, const float* __restrict__ lnfb,
                     float* __restrict__ out) {
  __shared__ short xh[64 * PH];   // x
  __shared__ short qh[64 * PH];   // Q -> ctx -> ffn-h (own rows only)
  __shared__ short kh[64 * PH];   // K (cross-wave read)
  __shared__ short vt[64 * PH];   // V^T (cross-wave read)
  __shared__ short s0[64 * PH];   // scores/P (own rows only)
  __shared__ int   sidx[64];

  const int t = threadIdx.x;
  const int lane = t & 63;
  const int mt = t >> 6;
  const int quad = lane >> 4;
  const int c0 = lane & 15;
  const int b = blockIdx.x;
  const int arow = mt * 16 + c0;   // own-row index for A-frags

  if (t < 64) sidx[t] = (t < SS) ? seq[b * SS + t] : 0;
  __syncthreads();   // barrier 1 (sidx)

  const int len = lengths[b];
  const float alpha = (len <= 10) ? 0.3f : ((len >= 50) ? 0.7f : 0.5f);
  const float isq = 0.17677669529663687f;  // 1/sqrt(32)

  // ---- phase 0a: fused GNN-average rows (own rows) -> qh
#pragma unroll
  for (int ir = 0; ir < 16; ++ir) {
    int s = mt * 16 + ir;
    short v = 0;
    if (s < SS) v = avgh[(size_t)sidx[s] * SD + lane];
    qh[s * PH + lane] = v;
  }

  // ---- phase 0b: gnn projection + blend + pos -> xh (own rows; no barrier:
  //      qh own rows written by this wave)
  {
    f32x4 o4[4];
    mm64(qh, pwB, arow, quad, lane, o4);
#pragma unroll
    for (int nt = 0; nt < 4; ++nt) {
      int c = nt * 16 + c0;
      float pbv = pbias[c];
#pragma unroll
      for (int r = 0; r < 4; ++r) {
        int row = mt * 16 + quad * 4 + r;
        short ov = 0;
        if (row < SS) {
          float g = o4[nt][r] + pbv;
          float xv = alpha * bert[(size_t)sidx[row] * SD + c] +
                     (1.f - alpha) * g + pos[row * SD + c];
          ov = f2b(xv);
        }
        xh[row * PH + c] = ov;
      }
    }
  }

#pragma unroll 1
  for (int blk = 0; blk < NBLK; ++blk) {
    const short* Wq = wqB + blk * 4096;
    const short* Wk = wkB + blk * 4096;
    const short* Wv = wvB + blk * 4096;
    const short* Wo = woB + blk * 4096;
    const short* W1 = w1B + blk * 16384;
    const short* W2 = w2B + blk * 16384;

    __syncthreads();   // layer-top: kh/vt safe to rewrite (prev readers done)

    // ---- Q -> qh, K -> kh (own rows), V -> vt (own seq-columns, transposed)
    {
      f32x4 o4[4];
      mm64(xh, Wq, arow, quad, lane, o4);
#pragma unroll
      for (int nt = 0; nt < 4; ++nt) {
        int c = nt * 16 + c0;
#pragma unroll
        for (int r = 0; r < 4; ++r) qh[(mt * 16 + quad * 4 + r) * PH + c] = f2b(o4[nt][r]);
      }
      mm64(xh, Wk, arow, quad, lane, o4);
#pragma unroll
      for (int nt = 0; nt < 4; ++nt) {
        int c = nt * 16 + c0;
#pragma unroll
        for (int r = 0; r < 4; ++r) kh[(mt * 16 + quad * 4 + r) * PH + c] = f2b(o4[nt][r]);
      }
      mm64(xh, Wv, arow, quad, lane, o4);
#pragma unroll
      for (int nt = 0; nt < 4; ++nt) {
        int dim = nt * 16 + c0;
        unsigned p0 = packb(o4[nt][0], o4[nt][1]);
        unsigned p1 = packb(o4[nt][2], o4[nt][3]);
        *(uint2*)(vt + (size_t)dim * PH + mt * 16 + quad * 4) = make_uint2(p0, p1);
      }
    }
    __syncthreads();   // kh/vt visible to all waves

    // ---- per-head: scores -> softmax -> ctx (all own-rows; no barriers)
#pragma unroll
    for (int h = 0; h < 2; ++h) {
      // scores: S[q][key] for own q-rows, all 64 key cols
      {
        bf16x8 aq = *(const bf16x8*)(qh + arow * PH + h * 32 + quad * 8);
#pragma unroll
        for (int nt = 0; nt < 4; ++nt) {
          int key = nt * 16 + c0;
          bf16x8 bk = *(const bf16x8*)(kh + key * PH + h * 32 + quad * 8);
          f32x4 acc = {0.f, 0.f, 0.f, 0.f};
          acc = __builtin_amdgcn_mfma_f32_16x16x32_bf16(aq, bk, acc, 0, 0, 0);
          bool km = (key < SS) && (sidx[key] != 0);
#pragma unroll
          for (int r = 0; r < 4; ++r) {
            int q = mt * 16 + quad * 4 + r;
            s0[q * PH + key] = f2b(km ? acc[r] * isq : -1e9f);
          }
        }
      }
      // softmax over own rows: lane -> row mt*16+(lane&15), quad -> col group
      {
        int row = mt * 16 + c0;
        short* base = s0 + row * PH + quad * 16;
        float v[16];
        float mx = -1e30f;
#pragma unroll
        for (int i = 0; i < 16; ++i) { v[i] = b2f(base[i]); mx = fmaxf(mx, v[i]); }
        mx = fmaxf(mx, __shfl_xor(mx, 16, 64));
        mx = fmaxf(mx, __shfl_xor(mx, 32, 64));
        float sm = 0.f;
#pragma unroll
        for (int i = 0; i < 16; ++i) {
          int col = quad * 16 + i;
          float e = (col < SS) ? __expf(v[i] - mx) : 0.f;
          v[i] = e;
          sm += e;
        }
        sm += __shfl_xor(sm, 16, 64);
        sm += __shfl_xor(sm, 32, 64);
        float inv = 1.f / sm;
        short o[16];
#pragma unroll
        for (int i = 0; i < 16; ++i) o[i] = f2b(v[i] * inv);
        *(bf16x8*)(base) = *(bf16x8*)(o);
        *(bf16x8*)(base + 8) = *(bf16x8*)(o + 8);
      }
      // ctx_h = P V_h -> overwrite qh own rows, cols h*32..h*32+31
      {
        bf16x8 a0 = *(const bf16x8*)(s0 + arow * PH + quad * 8);
        bf16x8 a1 = *(const bf16x8*)(s0 + arow * PH + 32 + quad * 8);
#pragma unroll
        for (int nt = 0; nt < 2; ++nt) {
          int dim = h * 32 + nt * 16 + c0;
          bf16x8 b0 = *(const bf16x8*)(vt + (size_t)dim * PH + quad * 8);
          bf16x8 b1v = *(const bf16x8*)(vt + (size_t)dim * PH + 32 + quad * 8);
          f32x4 acc = {0.f, 0.f, 0.f, 0.f};
          acc = __builtin_amdgcn_mfma_f32_16x16x32_bf16(a0, b0, acc, 0, 0, 0);
          acc = __builtin_amdgcn_mfma_f32_16x16x32_bf16(a1, b1v, acc, 0, 0, 0);
#pragma unroll
          for (int r = 0; r < 4; ++r)
            qh[(mt * 16 + quad * 4 + r) * PH + dim] = f2b(acc[r]);
        }
      }
    }

    // ---- O-projection + residual + LN1 -> xh (own rows)
    {
      f32x4 o4[4];
      mm64(qh, Wo, arow, quad, lane, o4);
      ln_epilogue(o4, xh, ln1g + blk * SD, ln1b + blk * SD, nullptr, mt, quad, c0);
    }

    // ---- FFN, own rows, no barriers (intra-wave LDS ordering)
    f32x4 facc[4];
#pragma unroll
    for (int nt = 0; nt < 4; ++nt) facc[nt] = (f32x4){0.f, 0.f, 0.f, 0.f};
#pragma unroll 1
    for (int c = 0; c < 4; ++c) {
      {
        bf16x8 a0 = *(const bf16x8*)(xh + arow * PH + quad * 8);
        bf16x8 a1 = *(const bf16x8*)(xh + arow * PH + 32 + quad * 8);
#pragma unroll
        for (int nt = 0; nt < 4; ++nt) {
          int ntg = c * 4 + nt;
          f32x4 acc = {0.f, 0.f, 0.f, 0.f};
          acc = __builtin_amdgcn_mfma_f32_16x16x32_bf16(a0, ldB(W1, 0 * 16 + ntg, lane), acc, 0, 0, 0);
          acc = __builtin_amdgcn_mfma_f32_16x16x32_bf16(a1, ldB(W1, 1 * 16 + ntg, lane), acc, 0, 0, 0);
          int cc = nt * 16 + c0;
          float b1v = b1[blk * 256 + c * 64 + cc];
#pragma unroll
          for (int r = 0; r < 4; ++r)
            qh[(mt * 16 + quad * 4 + r) * PH + cc] = f2b(gelu_tanh(acc[r] + b1v));
        }
      }
      {
        bf16x8 a0 = *(const bf16x8*)(qh + arow * PH + quad * 8);
        bf16x8 a1 = *(const bf16x8*)(qh + arow * PH + 32 + quad * 8);
#pragma unroll
        for (int nt = 0; nt < 4; ++nt) {
          facc[nt] = __builtin_amdgcn_mfma_f32_16x16x32_bf16(a0, ldB(W2, (2 * c) * 4 + nt, lane), facc[nt], 0, 0, 0);
          facc[nt] = __builtin_amdgcn_mfma_f32_16x16x32_bf16(a1, ldB(W2, (2 * c + 1) * 4 + nt, lane), facc[nt], 0, 0, 0);
        }
      }
    }

    // ---- residual + b2 + LN2 -> xh (own rows)
    ln_epilogue(facc, xh, ln2g + blk * SD, ln2b + blk * SD, b2 + blk * SD, mt, quad, c0);
  }
  __syncthreads();   // final: xh fully written by all waves

  // ---- final LN + gather row (lengths-1)
  if (mt == 0) {
    int sl = len - 1;
    float val = b2f(xh[sl * PH + lane]);
    float2 ss = wred_sum2(val, val * val);
    float m = ss.x * (1.f / 64);
    float var = fmaxf(ss.y * (1.f / 64) - m * m, 0.f);
    float rs = rsqrtf(var + 1e-5f);
    out[b * SD + lane] = (val - m) * rs * lnfg[lane] + lnfb[lane];
  }
}

// ---------------------------------------------------------------------------
extern "C" void kernel_launch(void* const* d_in, const int* in_sizes, int n_in,
                              void* d_out, int out_size, void* d_ws, size_t ws_size,
                              hipStream_t stream) {
  const int*   seq   = (const int*)d_in[0];
  const int*   lens  = (const int*)d_in[1];
  const int*   ei    = (const int*)d_in[2];
  const float* ew    = (const float*)d_in[3];
  const float* bert  = (const float*)d_in[4];
  const float* gnn   = (const float*)d_in[5];
  const float* pw    = (const float*)d_in[6];
  const float* pb    = (const float*)d_in[7];
  const float* pos   = (const float*)d_in[8];
  const float* wq    = (const float*)d_in[9];
  const float* wk    = (const float*)d_in[10];
  const float* wv    = (const float*)d_in[11];
  const float* wo    = (const float*)d_in[12];
  const float* w1    = (const float*)d_in[13];
  const float* b1    = (const float*)d_in[14];
  const float* w2    = (const float*)d_in[15];
  const float* b2    = (const float*)d_in[16];
  const float* ln1g  = (const float*)d_in[17];
  const float* ln1b  = (const float*)d_in[18];
  const float* ln2g  = (const float*)d_in[19];
  const float* ln2b  = (const float*)d_in[20];
  const float* lnfg  = (const float*)d_in[21];
  const float* lnfb  = (const float*)d_in[22];
  float* out = (float*)d_out;

  const int E = in_sizes[2] / 2;          // 1,000,000
  const int B = in_sizes[0] / SS;         // 1024
  const int N = in_sizes[4] / SD;         // 100,001

  const int* esrc = ei;
  const int* edst = ei + E;

  // ---- workspace layout
  short* pwB = (short*)d_ws;              // 4096 halves
  short* wqB = pwB + 4096;                // 8192
  short* wkB = wqB + 8192;
  short* wvB = wkB + 8192;
  short* woB = wvB + 8192;
  short* w1B = woB + 8192;                // 32768
  short* w2B = w1B + 32768;               // 32768
  unsigned* gnnh = (unsigned*)(w2B + 32768);   // N*32 uints (bf16 pairs)
  unsigned* g1xh = gnnh + (size_t)N * 32;
  unsigned* avgh = g1xh + (size_t)N * 32;
  const int NCH = (N + 1023) >> 10;
  const int PADN = NCH << 10;
  int* cnt  = (int*)(avgh + (size_t)N * 32);
  int* bsum = cnt + PADN;
  int* rp   = bsum + 128;
  int* wp   = rp + (N + 1);
  int2* ep = (int2*)((((size_t)(wp + N)) + 15) & ~(size_t)15);
  size_t need = (size_t)((char*)(ep + E) - (char*)d_ws);

  // fallback fp32 tables (overlay the CSR/scan region)
  float* g1x = (float*)cnt;
  float* g2x = g1x + (size_t)N * SD;
  size_t need_fb = (size_t)((char*)(g2x + (size_t)N * SD) - (char*)d_ws);

  // ---- weight prep (1 launch)
  prep_all<<<50, 256, 0, stream>>>(pw, wq, wk, wv, wo, w1, w2,
                                   pwB, wqB, wkB, wvB, woB, w1B, w2B);

  const int n32 = N * 32;
  if (ws_size >= need && NCH <= 128) {
    hipMemsetAsync(cnt, 0, (size_t)PADN * sizeof(int), stream);
    cvt_hist<<<(n32 + 255) / 256, 256, 0, stream>>>(gnn, gnnh, n32, edst, cnt, E);
    gnn_chunk_sums<<<NCH, 256, 0, stream>>>(cnt, bsum);
    gnn_scan_bsum<<<1, 128, 0, stream>>>(bsum, NCH);
    gnn_chunk_scan<<<NCH, 256, 0, stream>>>(cnt, bsum, rp, wp, N);
    gnn_build<<<(E + 255) / 256, 256, 0, stream>>>(esrc, edst, ew, wp, ep, E);
    const int nb = (N + 7) / 8;
    gnn_gather1<<<nb, 256, 0, stream>>>(gnnh, rp, ep, g1xh, N);
    gnn_gather_avg<<<nb, 256, 0, stream>>>(g1xh, rp, ep, gnn, avgh, N);
  } else if (ws_size >= need_fb) {
    hipMemsetAsync(g1x, 0, (size_t)2 * N * SD * sizeof(float), stream);
    const long total = (long)E * 64;
    const int sblocks = (int)((total + 255) / 256);
    gnn_scatter<<<sblocks, 256, 0, stream>>>(gnn, esrc, edst, ew, g1x, E);
    gnn_scatter<<<sblocks, 256, 0, stream>>>(g1x, esrc, edst, ew, g2x, E);
    avg_from_f32<<<(n32 + 255) / 256, 256, 0, stream>>>(gnn, g1x, g2x, avgh, n32);
  }

  seq_transformer<<<B, 256, 0, stream>>>(
      seq, lens, bert, (const short*)avgh, pb, pos,
      pwB, wqB, wkB, wvB, woB, w1B, w2B,
      b1, b2, ln1g, ln1b, ln2g, ln2b, lnfg, lnfb, out);
}